// Round 1
// baseline (1462.268 us; speedup 1.0000x reference)
//
#include <hip/hip_runtime.h>

#define NN 50000
#define NE 1600000
constexpr float LN_EPS = 1e-5f;

__device__ __forceinline__ float gelu_f(float x){
  return 0.5f * x * (1.0f + erff(x * 0.70710678118654752440f));
}

// ---------------- node embedding MLP: x[N,16] -> h[N,32] ----------------
__global__ __launch_bounds__(256) void embed_kernel(
    const float* __restrict__ x,
    const float* __restrict__ W1, const float* __restrict__ b1,
    const float* __restrict__ g1, const float* __restrict__ bb1,
    const float* __restrict__ W2, const float* __restrict__ b2,
    const float* __restrict__ g2, const float* __restrict__ bb2,
    float* __restrict__ h, float* __restrict__ pre)
{
  int n = blockIdx.x*256 + threadIdx.x;
  if(n >= NN) return;
  const float rs = rsqrtf(1.0f + LN_EPS);   // BN eval scale with running var=1
  float xv[16];
  const float4* xp = (const float4*)(x + n*16);
  #pragma unroll
  for(int i=0;i<4;i++){ float4 t=xp[i]; xv[4*i]=t.x; xv[4*i+1]=t.y; xv[4*i+2]=t.z; xv[4*i+3]=t.w; }
  float a1[64];
  #pragma unroll
  for(int j=0;j<64;j++) a1[j]=b1[j];
  #pragma unroll
  for(int k=0;k<16;k++){
    float xk=xv[k];
    #pragma unroll
    for(int j=0;j<64;j++) a1[j] += xk * W1[k*64+j];   // uniform addr -> s_load
  }
  #pragma unroll
  for(int j=0;j<64;j++) a1[j] = gelu_f(a1[j]*(g1[j]*rs) + bb1[j]);
  float a2[32];
  #pragma unroll
  for(int j=0;j<32;j++) a2[j]=b2[j];
  #pragma unroll
  for(int k=0;k<64;k++){
    float tk=a1[k];
    #pragma unroll
    for(int j=0;j<32;j++) a2[j] += tk * W2[k*32+j];
  }
  #pragma unroll
  for(int j=0;j<32;j++){
    float v = gelu_f(a2[j]*(g2[j]*rs) + bb2[j]);
    h[n*32+j]=v; pre[n*32+j]=v;
  }
}

// ---------------- CSR build (counting sort by dst) ----------------
__global__ __launch_bounds__(256) void hist_kernel(const int* __restrict__ ei, int* __restrict__ cnt){
  int e = blockIdx.x*256 + threadIdx.x;
  if(e < NE) atomicAdd(&cnt[ei[NE+e]], 1);
}

#define CHUNK 49  // 1024*49 = 50176 >= 50000
__global__ __launch_bounds__(1024) void scan_kernel(const int* __restrict__ deg, int* __restrict__ row_ptr){
  __shared__ int sums[1024];
  int t = threadIdx.x;
  int base = t*CHUNK;
  int s=0;
  for(int i=0;i<CHUNK;i++){ int idx=base+i; if(idx<NN) s += deg[idx]; }
  sums[t]=s;
  __syncthreads();
  for(int off=1; off<1024; off<<=1){
    int v = (t>=off) ? sums[t-off] : 0;
    __syncthreads();
    sums[t] += v;
    __syncthreads();
  }
  int run = (t>0) ? sums[t-1] : 0;
  for(int i=0;i<CHUNK;i++){ int idx=base+i; if(idx<NN){ row_ptr[idx]=run; run += deg[idx]; } }
  if(t==0) row_ptr[NN] = sums[1023];
}

__global__ __launch_bounds__(256) void fill_kernel(const int* __restrict__ ei,
    const int* __restrict__ row_ptr, int* __restrict__ cur, int* __restrict__ csr_src){
  int e = blockIdx.x*256 + threadIdx.x;
  if(e < NE){
    int d = ei[NE+e];
    int pos = atomicAdd(&cur[d], 1);
    csr_src[row_ptr[d] + pos] = ei[e];
  }
}

// ---------------- per-layer node-side precompute: P,Q,R ----------------
// P = h@Wm_top + msg_b ; Q = h@Wm_bot ; R = h@Wu_top + upd_b
__global__ __launch_bounds__(256) void pqr_kernel(
    const float* __restrict__ h,
    const float* __restrict__ Wm, const float* __restrict__ bm,
    const float* __restrict__ Wu, const float* __restrict__ bu,
    float* __restrict__ P, float* __restrict__ Q, float* __restrict__ R)
{
  int n = blockIdx.x*256 + threadIdx.x;
  if(n >= NN) return;
  float hv[32];
  const float4* hp = (const float4*)(h + n*32);
  #pragma unroll
  for(int i=0;i<8;i++){ float4 t=hp[i]; hv[4*i]=t.x; hv[4*i+1]=t.y; hv[4*i+2]=t.z; hv[4*i+3]=t.w; }
  float ap[32], aq[32], ar[32];
  #pragma unroll
  for(int j=0;j<32;j++){ ap[j]=bm[j]; aq[j]=0.f; ar[j]=bu[j]; }
  #pragma unroll
  for(int k=0;k<32;k++){
    float hk = hv[k];
    #pragma unroll
    for(int j=0;j<32;j++){
      ap[j] += hk * Wm[k*32+j];        // top rows 0..31  (x_i / dst side)
      aq[j] += hk * Wm[(32+k)*32+j];   // bottom rows 32..63 (x_j / src side)
      ar[j] += hk * Wu[k*32+j];        // upd top (h side)
    }
  }
  #pragma unroll
  for(int j=0;j<32;j++){ P[n*32+j]=ap[j]; Q[n*32+j]=aq[j]; R[n*32+j]=ar[j]; }
}

// -------- fused message+aggregate+update, one node per lane, CSR pull --------
__global__ __launch_bounds__(256) void msg_upd_kernel(
    const float* __restrict__ P, const float* __restrict__ Q,
    const float* __restrict__ R,
    const int* __restrict__ row_ptr, const int* __restrict__ csr_src,
    const float* __restrict__ Ub,    // upd_W rows 32..63: [32][32]
    const float* __restrict__ mg, const float* __restrict__ mb,
    const float* __restrict__ ug, const float* __restrict__ ub,
    float* __restrict__ h)
{
  int n = blockIdx.x*256 + threadIdx.x;
  if(n >= NN) return;
  float p[32], agg[32];
  const float4* pp = (const float4*)(P + n*32);
  #pragma unroll
  for(int i=0;i<8;i++){ float4 t=pp[i]; p[4*i]=t.x; p[4*i+1]=t.y; p[4*i+2]=t.z; p[4*i+3]=t.w; }
  #pragma unroll
  for(int j=0;j<32;j++) agg[j]=0.f;
  int e0 = row_ptr[n], e1 = row_ptr[n+1];
  for(int e=e0; e<e1; e++){
    int s = csr_src[e];
    const float4* q4 = (const float4*)(Q + s*32);
    float v[32];
    #pragma unroll
    for(int i=0;i<8;i++){ float4 t=q4[i];
      v[4*i]=p[4*i]+t.x; v[4*i+1]=p[4*i+1]+t.y; v[4*i+2]=p[4*i+2]+t.z; v[4*i+3]=p[4*i+3]+t.w; }
    float s0=0,s1=0,s2=0,s3=0;
    #pragma unroll
    for(int i=0;i<8;i++){ s0+=v[4*i]; s1+=v[4*i+1]; s2+=v[4*i+2]; s3+=v[4*i+3]; }
    float mean = ((s0+s1)+(s2+s3)) * 0.03125f;
    s0=s1=s2=s3=0.f;
    #pragma unroll
    for(int i=0;i<8;i++){
      float d0=v[4*i]-mean, d1=v[4*i+1]-mean, d2=v[4*i+2]-mean, d3=v[4*i+3]-mean;
      s0+=d0*d0; s1+=d1*d1; s2+=d2*d2; s3+=d3*d3;
      v[4*i]=d0; v[4*i+1]=d1; v[4*i+2]=d2; v[4*i+3]=d3;
    }
    float rstd = rsqrtf(((s0+s1)+(s2+s3))*0.03125f + LN_EPS);
    #pragma unroll
    for(int j=0;j<32;j++) agg[j] += gelu_f(v[j]*rstd*mg[j] + mb[j]);
  }
  // update MLP: u = R + agg @ Ub, then LN, gelu, residual into h
  float u[32];
  const float4* rp = (const float4*)(R + n*32);
  #pragma unroll
  for(int i=0;i<8;i++){ float4 t=rp[i]; u[4*i]=t.x; u[4*i+1]=t.y; u[4*i+2]=t.z; u[4*i+3]=t.w; }
  #pragma unroll
  for(int k=0;k<32;k++){
    float a = agg[k];
    #pragma unroll
    for(int j=0;j<32;j++) u[j] += a * Ub[k*32+j];   // uniform addr -> s_load
  }
  float s0=0,s1=0,s2=0,s3=0;
  #pragma unroll
  for(int i=0;i<8;i++){ s0+=u[4*i]; s1+=u[4*i+1]; s2+=u[4*i+2]; s3+=u[4*i+3]; }
  float mean = ((s0+s1)+(s2+s3)) * 0.03125f;
  s0=s1=s2=s3=0.f;
  #pragma unroll
  for(int i=0;i<8;i++){
    float d0=u[4*i]-mean, d1=u[4*i+1]-mean, d2=u[4*i+2]-mean, d3=u[4*i+3]-mean;
    s0+=d0*d0; s1+=d1*d1; s2+=d2*d2; s3+=d3*d3;
    u[4*i]=d0; u[4*i+1]=d1; u[4*i+2]=d2; u[4*i+3]=d3;
  }
  float rstd = rsqrtf(((s0+s1)+(s2+s3))*0.03125f + LN_EPS);
  #pragma unroll
  for(int j=0;j<32;j++) h[n*32+j] += gelu_f(u[j]*rstd*ug[j] + ub[j]);
}

// ---------------- final: hW1 = (h+pre) @ fin_W1 per node ----------------
__global__ __launch_bounds__(256) void hfin_kernel(
    const float* __restrict__ h, const float* __restrict__ pre,
    const float* __restrict__ W1, float* __restrict__ hW1)
{
  int n = blockIdx.x*256 + threadIdx.x;
  if(n >= NN) return;
  float hp[32];
  #pragma unroll
  for(int k=0;k<32;k++) hp[k] = h[n*32+k] + pre[n*32+k];
  float acc[64];
  #pragma unroll
  for(int j=0;j<64;j++) acc[j]=0.f;
  #pragma unroll
  for(int k=0;k<32;k++){
    float hk = hp[k];
    #pragma unroll
    for(int j=0;j<64;j++) acc[j] += hk * W1[k*64+j];
  }
  #pragma unroll
  for(int j=0;j<64;j++) hW1[n*64+j] = acc[j];
}

// ---------------- final per-edge: one edge per lane ----------------
__global__ __launch_bounds__(256) void final_kernel(
    const float* __restrict__ hW1, const int* __restrict__ ei,
    const float* __restrict__ b1, const float* __restrict__ bg, const float* __restrict__ bb,
    const float* __restrict__ W2, const float* __restrict__ b2,
    float* __restrict__ out)
{
  int e = blockIdx.x*256 + threadIdx.x;
  if(e >= NE) return;
  int s = ei[e], d = ei[NE+e];
  const float4* pd = (const float4*)(hW1 + d*64);
  const float4* ps = (const float4*)(hW1 + s*64);
  const float rs = rsqrtf(1.0f + LN_EPS);
  float o0=b2[0], o1=b2[1], o2=b2[2];
  #pragma unroll
  for(int i=0;i<16;i++){
    float4 a4 = pd[i], c4 = ps[i];
    float vv0=a4.x-c4.x, vv1=a4.y-c4.y, vv2=a4.z-c4.z, vv3=a4.w-c4.w;
    int j = 4*i;
    float t0 = gelu_f((vv0 + b1[j+0])*(bg[j+0]*rs) + bb[j+0]);
    float t1 = gelu_f((vv1 + b1[j+1])*(bg[j+1]*rs) + bb[j+1]);
    float t2 = gelu_f((vv2 + b1[j+2])*(bg[j+2]*rs) + bb[j+2]);
    float t3 = gelu_f((vv3 + b1[j+3])*(bg[j+3]*rs) + bb[j+3]);
    o0 += t0*W2[(j+0)*3+0] + t1*W2[(j+1)*3+0] + t2*W2[(j+2)*3+0] + t3*W2[(j+3)*3+0];
    o1 += t0*W2[(j+0)*3+1] + t1*W2[(j+1)*3+1] + t2*W2[(j+2)*3+1] + t3*W2[(j+3)*3+1];
    o2 += t0*W2[(j+0)*3+2] + t1*W2[(j+1)*3+2] + t2*W2[(j+2)*3+2] + t3*W2[(j+3)*3+2];
  }
  out[e*3+0]=o0; out[e*3+1]=o1; out[e*3+2]=o2;
}

extern "C" void kernel_launch(void* const* d_in, const int* in_sizes, int n_in,
                              void* d_out, int out_size, void* d_ws, size_t ws_size,
                              hipStream_t stream)
{
  (void)in_sizes; (void)n_in; (void)out_size; (void)ws_size;
  const float* x     = (const float*)d_in[0];
  const int*   ei    = (const int*)d_in[1];
  const float* eW1   = (const float*)d_in[2];
  const float* eb1   = (const float*)d_in[3];
  const float* ebn1g = (const float*)d_in[4];
  const float* ebn1b = (const float*)d_in[5];
  const float* eW2   = (const float*)d_in[6];
  const float* eb2   = (const float*)d_in[7];
  const float* ebn2g = (const float*)d_in[8];
  const float* ebn2b = (const float*)d_in[9];
  const float* msgW  = (const float*)d_in[10];
  const float* msgb  = (const float*)d_in[11];
  const float* msglng= (const float*)d_in[12];
  const float* msglnb= (const float*)d_in[13];
  const float* updW  = (const float*)d_in[14];
  const float* updb  = (const float*)d_in[15];
  const float* updlng= (const float*)d_in[16];
  const float* updlnb= (const float*)d_in[17];
  const float* fW1   = (const float*)d_in[18];
  const float* fb1   = (const float*)d_in[19];
  const float* fbng  = (const float*)d_in[20];
  const float* fbnb  = (const float*)d_in[21];
  const float* fW2   = (const float*)d_in[22];
  const float* fb2   = (const float*)d_in[23];
  float* out = (float*)d_out;

  // workspace layout (floats): h, pre, P, Q, R  each NN*32; hW1 aliases P..Q (NN*64)
  float* f   = (float*)d_ws;
  float* h   = f;
  float* pre = f + 1*NN*32;
  float* P   = f + 2*NN*32;
  float* Q   = f + 3*NN*32;
  float* R   = f + 4*NN*32;
  float* hW1 = P;  // reused after GNN layers (NN*64 floats spans P and Q)
  int* ip      = (int*)(f + 5*NN*32);
  int* row_ptr = ip;            // NN+1
  int* cnt     = ip + NN + 1;   // NN
  int* csr     = ip + 2*NN + 1; // NE

  embed_kernel<<<(NN+255)/256, 256, 0, stream>>>(x, eW1, eb1, ebn1g, ebn1b,
                                                 eW2, eb2, ebn2g, ebn2b, h, pre);
  hipMemsetAsync(cnt, 0, NN*sizeof(int), stream);
  hist_kernel<<<(NE+255)/256, 256, 0, stream>>>(ei, cnt);
  scan_kernel<<<1, 1024, 0, stream>>>(cnt, row_ptr);
  hipMemsetAsync(cnt, 0, NN*sizeof(int), stream);
  fill_kernel<<<(NE+255)/256, 256, 0, stream>>>(ei, row_ptr, cnt, csr);

  for(int l=0; l<3; l++){
    pqr_kernel<<<(NN+255)/256, 256, 0, stream>>>(h,
        msgW + l*2048, msgb + l*32, updW + l*2048, updb + l*32, P, Q, R);
    msg_upd_kernel<<<(NN+255)/256, 256, 0, stream>>>(P, Q, R, row_ptr, csr,
        updW + l*2048 + 1024,
        msglng + l*32, msglnb + l*32, updlng + l*32, updlnb + l*32, h);
  }

  hfin_kernel<<<(NN+255)/256, 256, 0, stream>>>(h, pre, fW1, hW1);
  final_kernel<<<(NE+255)/256, 256, 0, stream>>>(hW1, ei, fb1, fbng, fbnb, fW2, fb2, out);
}

// Round 2
// 754.919 us; speedup vs baseline: 1.9370x; 1.9370x over previous
//
#include <hip/hip_runtime.h>

#define NN 50000
#define NE 1600000
constexpr float LN_EPS = 1e-5f;

typedef _Float16 half8 __attribute__((ext_vector_type(8)));

// Branchless erf-GELU: Abramowitz-Stegun 7.1.26, |eps| <= 1.5e-7
__device__ __forceinline__ float gelu_f(float x){
  float ax = fabsf(x) * 0.70710678118654752440f;
  float t  = __builtin_amdgcn_rcpf(fmaf(0.3275911f, ax, 1.0f));
  float e  = __expf(-ax*ax);
  float p  = t*fmaf(t, fmaf(t, fmaf(t, fmaf(t, 1.061405429f, -1.453152027f),
                                    1.421413741f), -0.284496736f), 0.254829592f);
  float er = fmaf(-p, e, 1.0f);
  return 0.5f * x * (1.0f + copysignf(er, x));
}

// ---------------- node embedding MLP: x[N,16] -> h[N,32] ----------------
__global__ __launch_bounds__(256) void embed_kernel(
    const float* __restrict__ x,
    const float* __restrict__ W1, const float* __restrict__ b1,
    const float* __restrict__ g1, const float* __restrict__ bb1,
    const float* __restrict__ W2, const float* __restrict__ b2,
    const float* __restrict__ g2, const float* __restrict__ bb2,
    float* __restrict__ h, float* __restrict__ pre)
{
  int n = blockIdx.x*256 + threadIdx.x;
  if(n >= NN) return;
  const float rs = rsqrtf(1.0f + LN_EPS);
  float xv[16];
  const float4* xp = (const float4*)(x + n*16);
  #pragma unroll
  for(int i=0;i<4;i++){ float4 t=xp[i]; xv[4*i]=t.x; xv[4*i+1]=t.y; xv[4*i+2]=t.z; xv[4*i+3]=t.w; }
  float a1[64];
  #pragma unroll
  for(int j=0;j<64;j++) a1[j]=b1[j];
  #pragma unroll
  for(int k=0;k<16;k++){
    float xk=xv[k];
    #pragma unroll
    for(int j=0;j<64;j++) a1[j] += xk * W1[k*64+j];
  }
  #pragma unroll
  for(int j=0;j<64;j++) a1[j] = gelu_f(a1[j]*(g1[j]*rs) + bb1[j]);
  float a2[32];
  #pragma unroll
  for(int j=0;j<32;j++) a2[j]=b2[j];
  #pragma unroll
  for(int k=0;k<64;k++){
    float tk=a1[k];
    #pragma unroll
    for(int j=0;j<32;j++) a2[j] += tk * W2[k*32+j];
  }
  #pragma unroll
  for(int j=0;j<32;j++){
    float v = gelu_f(a2[j]*(g2[j]*rs) + bb2[j]);
    h[n*32+j]=v; pre[n*32+j]=v;
  }
}

// ---------------- CSR build (counting sort by dst) ----------------
__global__ __launch_bounds__(256) void hist_kernel(const int* __restrict__ ei, int* __restrict__ cnt){
  int e = blockIdx.x*256 + threadIdx.x;
  if(e < NE) atomicAdd(&cnt[ei[NE+e]], 1);
}

#define CHUNK 49  // 1024*49 = 50176 >= 50000
__global__ __launch_bounds__(1024) void scan_kernel(const int* __restrict__ deg, int* __restrict__ row_ptr){
  __shared__ int sums[1024];
  int t = threadIdx.x;
  int base = t*CHUNK;
  int s=0;
  for(int i=0;i<CHUNK;i++){ int idx=base+i; if(idx<NN) s += deg[idx]; }
  sums[t]=s;
  __syncthreads();
  for(int off=1; off<1024; off<<=1){
    int v = (t>=off) ? sums[t-off] : 0;
    __syncthreads();
    sums[t] += v;
    __syncthreads();
  }
  int run = (t>0) ? sums[t-1] : 0;
  for(int i=0;i<CHUNK;i++){ int idx=base+i; if(idx<NN){ row_ptr[idx]=run; run += deg[idx]; } }
  if(t==0) row_ptr[NN] = sums[1023];
}

__global__ __launch_bounds__(256) void fill_kernel(const int* __restrict__ ei,
    const int* __restrict__ row_ptr, int* __restrict__ cur, int* __restrict__ csr_src){
  int e = blockIdx.x*256 + threadIdx.x;
  if(e < NE){
    int d = ei[NE+e];
    int pos = atomicAdd(&cur[d], 1);
    csr_src[row_ptr[d] + pos] = ei[e];
  }
}

// ---------------- per-layer node-side precompute: P,Q(fp16),R ----------------
__global__ __launch_bounds__(256) void pqr_kernel(
    const float* __restrict__ h,
    const float* __restrict__ Wm, const float* __restrict__ bm,
    const float* __restrict__ Wu, const float* __restrict__ bu,
    float* __restrict__ P, _Float16* __restrict__ Qh, float* __restrict__ R)
{
  int n = blockIdx.x*256 + threadIdx.x;
  if(n >= NN) return;
  float hv[32];
  const float4* hp = (const float4*)(h + n*32);
  #pragma unroll
  for(int i=0;i<8;i++){ float4 t=hp[i]; hv[4*i]=t.x; hv[4*i+1]=t.y; hv[4*i+2]=t.z; hv[4*i+3]=t.w; }
  float ap[32], aq[32], ar[32];
  #pragma unroll
  for(int j=0;j<32;j++){ ap[j]=bm[j]; aq[j]=0.f; ar[j]=bu[j]; }
  #pragma unroll
  for(int k=0;k<32;k++){
    float hk = hv[k];
    #pragma unroll
    for(int j=0;j<32;j++){
      ap[j] += hk * Wm[k*32+j];        // top rows (x_i / dst side)
      aq[j] += hk * Wm[(32+k)*32+j];   // bottom rows (x_j / src side)
      ar[j] += hk * Wu[k*32+j];        // upd top (h side)
    }
  }
  #pragma unroll
  for(int j=0;j<32;j++){ P[n*32+j]=ap[j]; R[n*32+j]=ar[j]; }
  half8* qo = (half8*)(Qh + (size_t)n*32);
  #pragma unroll
  for(int i=0;i<4;i++){
    half8 q;
    #pragma unroll
    for(int k=0;k<8;k++) q[k] = (_Float16)aq[8*i+k];
    qo[i] = q;
  }
}

// -------- message+aggregate: 8 lanes per node, CSR pull, in-wave combine --------
__global__ __launch_bounds__(256) void msg_kernel(
    const float* __restrict__ P, const _Float16* __restrict__ Qh,
    const int* __restrict__ row_ptr, const int* __restrict__ csr_src,
    const float* __restrict__ mg, const float* __restrict__ mb,
    float* __restrict__ aggO)
{
  int tid = blockIdx.x*256 + threadIdx.x;
  int n = tid >> 3, s = tid & 7;
  bool valid = (n < NN);
  float p[32], agg[32];
  #pragma unroll
  for(int j=0;j<32;j++) agg[j]=0.f;
  int e0=0, e1=0;
  if(valid){
    const float4* pp = (const float4*)(P + (size_t)n*32);
    #pragma unroll
    for(int i=0;i<8;i++){ float4 t=pp[i]; p[4*i]=t.x; p[4*i+1]=t.y; p[4*i+2]=t.z; p[4*i+3]=t.w; }
    e0 = row_ptr[n]; e1 = row_ptr[n+1];
  }
  for(int e=e0+s; e<e1; e+=8){
    int src = csr_src[e];
    const half8* q4 = (const half8*)(Qh + (size_t)src*32);
    float v[32];
    #pragma unroll
    for(int i=0;i<4;i++){
      half8 t = q4[i];
      #pragma unroll
      for(int k=0;k<8;k++) v[8*i+k] = p[8*i+k] + (float)t[k];
    }
    float s0=0,s1=0,s2=0,s3=0;
    #pragma unroll
    for(int i=0;i<8;i++){ s0+=v[4*i]; s1+=v[4*i+1]; s2+=v[4*i+2]; s3+=v[4*i+3]; }
    float mean = ((s0+s1)+(s2+s3)) * 0.03125f;
    s0=s1=s2=s3=0.f;
    #pragma unroll
    for(int i=0;i<8;i++){
      float d0=v[4*i]-mean, d1=v[4*i+1]-mean, d2=v[4*i+2]-mean, d3=v[4*i+3]-mean;
      s0+=d0*d0; s1+=d1*d1; s2+=d2*d2; s3+=d3*d3;
      v[4*i]=d0; v[4*i+1]=d1; v[4*i+2]=d2; v[4*i+3]=d3;
    }
    float rstd = rsqrtf(((s0+s1)+(s2+s3))*0.03125f + LN_EPS);
    #pragma unroll
    for(int j=0;j<32;j++) agg[j] += gelu_f(v[j]*rstd*mg[j] + mb[j]);
  }
  // combine the 8 partials (lane bits 0..2 == s)
  #pragma unroll
  for(int j=0;j<32;j++) agg[j] += __shfl_xor(agg[j], 1);
  #pragma unroll
  for(int j=0;j<32;j++) agg[j] += __shfl_xor(agg[j], 2);
  #pragma unroll
  for(int j=0;j<32;j++) agg[j] += __shfl_xor(agg[j], 4);
  if(valid && s==0){
    float4* ao = (float4*)(aggO + (size_t)n*32);
    #pragma unroll
    for(int i=0;i<8;i++){ float4 t; t.x=agg[4*i]; t.y=agg[4*i+1]; t.z=agg[4*i+2]; t.w=agg[4*i+3]; ao[i]=t; }
  }
}

// -------- update MLP: u = R + agg@Ub, LN, gelu, residual into h --------
__global__ __launch_bounds__(256) void upd_kernel(
    const float* __restrict__ aggI, const float* __restrict__ R,
    const float* __restrict__ Ub,
    const float* __restrict__ ug, const float* __restrict__ ub,
    float* __restrict__ h)
{
  int n = blockIdx.x*256 + threadIdx.x;
  if(n >= NN) return;
  float agg[32], u[32];
  const float4* ap = (const float4*)(aggI + (size_t)n*32);
  const float4* rp = (const float4*)(R + (size_t)n*32);
  #pragma unroll
  for(int i=0;i<8;i++){ float4 t=ap[i]; agg[4*i]=t.x; agg[4*i+1]=t.y; agg[4*i+2]=t.z; agg[4*i+3]=t.w; }
  #pragma unroll
  for(int i=0;i<8;i++){ float4 t=rp[i]; u[4*i]=t.x; u[4*i+1]=t.y; u[4*i+2]=t.z; u[4*i+3]=t.w; }
  #pragma unroll
  for(int k=0;k<32;k++){
    float a = agg[k];
    #pragma unroll
    for(int j=0;j<32;j++) u[j] += a * Ub[k*32+j];
  }
  float s0=0,s1=0,s2=0,s3=0;
  #pragma unroll
  for(int i=0;i<8;i++){ s0+=u[4*i]; s1+=u[4*i+1]; s2+=u[4*i+2]; s3+=u[4*i+3]; }
  float mean = ((s0+s1)+(s2+s3)) * 0.03125f;
  s0=s1=s2=s3=0.f;
  #pragma unroll
  for(int i=0;i<8;i++){
    float d0=u[4*i]-mean, d1=u[4*i+1]-mean, d2=u[4*i+2]-mean, d3=u[4*i+3]-mean;
    s0+=d0*d0; s1+=d1*d1; s2+=d2*d2; s3+=d3*d3;
    u[4*i]=d0; u[4*i+1]=d1; u[4*i+2]=d2; u[4*i+3]=d3;
  }
  float rstd = rsqrtf(((s0+s1)+(s2+s3))*0.03125f + LN_EPS);
  #pragma unroll
  for(int j=0;j<32;j++) h[(size_t)n*32+j] += gelu_f(u[j]*rstd*ug[j] + ub[j]);
}

// ---------------- final: y = ((h+pre) @ fin_W1) * bn_scale, stored fp16 ----------------
__global__ __launch_bounds__(256) void hfin_kernel(
    const float* __restrict__ h, const float* __restrict__ pre,
    const float* __restrict__ W1, const float* __restrict__ bg,
    _Float16* __restrict__ y)
{
  int n = blockIdx.x*256 + threadIdx.x;
  if(n >= NN) return;
  const float rs = rsqrtf(1.0f + LN_EPS);
  float hp[32];
  #pragma unroll
  for(int k=0;k<32;k++) hp[k] = h[(size_t)n*32+k] + pre[(size_t)n*32+k];
  float acc[64];
  #pragma unroll
  for(int j=0;j<64;j++) acc[j]=0.f;
  #pragma unroll
  for(int k=0;k<32;k++){
    float hk = hp[k];
    #pragma unroll
    for(int j=0;j<64;j++) acc[j] += hk * W1[k*64+j];
  }
  half8* yo = (half8*)(y + (size_t)n*64);
  #pragma unroll
  for(int i=0;i<8;i++){
    half8 q;
    #pragma unroll
    for(int k=0;k<8;k++) q[k] = (_Float16)(acc[8*i+k] * (bg[8*i+k]*rs));
    yo[i] = q;
  }
}

// ---------------- final per-edge: one edge per lane ----------------
__global__ __launch_bounds__(256) void final_kernel(
    const _Float16* __restrict__ y, const int* __restrict__ ei,
    const float* __restrict__ b1, const float* __restrict__ bg, const float* __restrict__ bb,
    const float* __restrict__ W2, const float* __restrict__ b2,
    float* __restrict__ out)
{
  int e = blockIdx.x*256 + threadIdx.x;
  if(e >= NE) return;
  int s = ei[e], d = ei[NE+e];
  const half8* pd = (const half8*)(y + (size_t)d*64);
  const half8* ps = (const half8*)(y + (size_t)s*64);
  const float rs = rsqrtf(1.0f + LN_EPS);
  float o0=b2[0], o1=b2[1], o2=b2[2];
  #pragma unroll
  for(int i=0;i<8;i++){
    half8 a8 = pd[i], c8 = ps[i];
    #pragma unroll
    for(int k=0;k<8;k++){
      int j = 8*i+k;
      float cj = fmaf(b1[j], bg[j]*rs, bb[j]);      // uniform -> SGPR math
      float t = gelu_f(((float)a8[k] - (float)c8[k]) + cj);
      o0 += t*W2[j*3+0]; o1 += t*W2[j*3+1]; o2 += t*W2[j*3+2];
    }
  }
  out[(size_t)e*3+0]=o0; out[(size_t)e*3+1]=o1; out[(size_t)e*3+2]=o2;
}

extern "C" void kernel_launch(void* const* d_in, const int* in_sizes, int n_in,
                              void* d_out, int out_size, void* d_ws, size_t ws_size,
                              hipStream_t stream)
{
  (void)in_sizes; (void)n_in; (void)out_size; (void)ws_size;
  const float* x     = (const float*)d_in[0];
  const int*   ei    = (const int*)d_in[1];
  const float* eW1   = (const float*)d_in[2];
  const float* eb1   = (const float*)d_in[3];
  const float* ebn1g = (const float*)d_in[4];
  const float* ebn1b = (const float*)d_in[5];
  const float* eW2   = (const float*)d_in[6];
  const float* eb2   = (const float*)d_in[7];
  const float* ebn2g = (const float*)d_in[8];
  const float* ebn2b = (const float*)d_in[9];
  const float* msgW  = (const float*)d_in[10];
  const float* msgb  = (const float*)d_in[11];
  const float* msglng= (const float*)d_in[12];
  const float* msglnb= (const float*)d_in[13];
  const float* updW  = (const float*)d_in[14];
  const float* updb  = (const float*)d_in[15];
  const float* updlng= (const float*)d_in[16];
  const float* updlnb= (const float*)d_in[17];
  const float* fW1   = (const float*)d_in[18];
  const float* fb1   = (const float*)d_in[19];
  const float* fbng  = (const float*)d_in[20];
  const float* fbnb  = (const float*)d_in[21];
  const float* fW2   = (const float*)d_in[22];
  const float* fb2   = (const float*)d_in[23];
  float* out = (float*)d_out;

  // workspace layout (4B units): h, pre, P, R, agg each NN*32 f32; Qh NN*32 fp16;
  // y (NN*64 fp16) aliases P; ints after Qh.
  float* f   = (float*)d_ws;
  float* h   = f;
  float* pre = f + 1*(size_t)NN*32;
  float* P   = f + 2*(size_t)NN*32;
  float* R   = f + 3*(size_t)NN*32;
  float* agg = f + 4*(size_t)NN*32;
  _Float16* Qh = (_Float16*)(f + 5*(size_t)NN*32);   // NN*32 halves = NN*16 floats
  _Float16* y  = (_Float16*)P;                        // NN*64 halves = NN*32 floats (fits)
  int* ip      = (int*)(f + 5*(size_t)NN*32 + (size_t)NN*16);
  int* row_ptr = ip;            // NN+1
  int* cnt     = ip + NN + 1;   // NN
  int* csr     = ip + 2*NN + 1; // NE

  embed_kernel<<<(NN+255)/256, 256, 0, stream>>>(x, eW1, eb1, ebn1g, ebn1b,
                                                 eW2, eb2, ebn2g, ebn2b, h, pre);
  hipMemsetAsync(cnt, 0, NN*sizeof(int), stream);
  hist_kernel<<<(NE+255)/256, 256, 0, stream>>>(ei, cnt);
  scan_kernel<<<1, 1024, 0, stream>>>(cnt, row_ptr);
  hipMemsetAsync(cnt, 0, NN*sizeof(int), stream);
  fill_kernel<<<(NE+255)/256, 256, 0, stream>>>(ei, row_ptr, cnt, csr);

  for(int l=0; l<3; l++){
    pqr_kernel<<<(NN+255)/256, 256, 0, stream>>>(h,
        msgW + l*2048, msgb + l*32, updW + l*2048, updb + l*32, P, Qh, R);
    msg_kernel<<<((NN*8)+255)/256, 256, 0, stream>>>(P, Qh, row_ptr, csr,
        msglng + l*32, msglnb + l*32, agg);
    upd_kernel<<<(NN+255)/256, 256, 0, stream>>>(agg, R,
        updW + l*2048 + 1024, updlng + l*32, updlnb + l*32, h);
  }

  hfin_kernel<<<(NN+255)/256, 256, 0, stream>>>(h, pre, fW1, fbng, y);
  final_kernel<<<(NE+255)/256, 256, 0, stream>>>(y, ei, fb1, fbng, fbnb, fW2, fb2, out);
}

// Round 3
// 699.752 us; speedup vs baseline: 2.0897x; 1.0788x over previous
//
#include <hip/hip_runtime.h>

#define NN 50000
#define NE 1600000
constexpr float LN_EPS = 1e-5f;

typedef _Float16 half8 __attribute__((ext_vector_type(8)));

// Branchless erf-GELU: Abramowitz-Stegun 7.1.26, |eps| <= 1.5e-7
__device__ __forceinline__ float gelu_f(float x){
  float ax = fabsf(x) * 0.70710678118654752440f;
  float t  = __builtin_amdgcn_rcpf(fmaf(0.3275911f, ax, 1.0f));
  float e  = __expf(-ax*ax);
  float p  = t*fmaf(t, fmaf(t, fmaf(t, fmaf(t, 1.061405429f, -1.453152027f),
                                    1.421413741f), -0.284496736f), 0.254829592f);
  float er = fmaf(-p, e, 1.0f);
  return 0.5f * x * (1.0f + copysignf(er, x));
}

// ---------------- CSR build ----------------
__global__ __launch_bounds__(256) void hist_kernel(const int* __restrict__ ei, int* __restrict__ cnt){
  int t = blockIdx.x*256 + threadIdx.x;
  if(t < NE/4){
    int4 d = ((const int4*)(ei + NE))[t];
    atomicAdd(&cnt[d.x],1); atomicAdd(&cnt[d.y],1);
    atomicAdd(&cnt[d.z],1); atomicAdd(&cnt[d.w],1);
  }
}

#define CHUNK 52  // 1024*52 = 53248 >= 50000
__global__ __launch_bounds__(1024) void scan_kernel(const int* __restrict__ deg, int* __restrict__ row_ptr){
  __shared__ int sums[1024];
  int t = threadIdx.x;
  int base = t*CHUNK;
  int4 v[13];
  int ssum = 0;
  #pragma unroll
  for(int i=0;i<13;i++){
    int idx = base + 4*i;
    if(idx + 3 < NN){
      v[i] = ((const int4*)deg)[(base>>2)+i];
    } else {
      v[i].x = (idx+0<NN)?deg[idx+0]:0; v[i].y = (idx+1<NN)?deg[idx+1]:0;
      v[i].z = (idx+2<NN)?deg[idx+2]:0; v[i].w = (idx+3<NN)?deg[idx+3]:0;
    }
    ssum += v[i].x + v[i].y + v[i].z + v[i].w;
  }
  sums[t]=ssum;
  __syncthreads();
  for(int off=1; off<1024; off<<=1){
    int vv = (t>=off) ? sums[t-off] : 0;
    __syncthreads();
    sums[t] += vv;
    __syncthreads();
  }
  int run = (t>0) ? sums[t-1] : 0;
  #pragma unroll
  for(int i=0;i<13;i++){
    int idx = base + 4*i;
    int4 o;
    o.x = run; run += v[i].x;
    o.y = run; run += v[i].y;
    o.z = run; run += v[i].z;
    o.w = run; run += v[i].w;
    if(idx + 3 < NN){
      ((int4*)row_ptr)[(base>>2)+i] = o;
    } else {
      if(idx+0<NN) row_ptr[idx+0]=o.x;
      if(idx+1<NN) row_ptr[idx+1]=o.y;
      if(idx+2<NN) row_ptr[idx+2]=o.z;
      if(idx+3<NN) row_ptr[idx+3]=o.w;
    }
  }
  if(t==1023) row_ptr[NN] = sums[1023];
}

__global__ __launch_bounds__(256) void fill_kernel(const int* __restrict__ ei,
    const int* __restrict__ row_ptr, int* __restrict__ cur, int* __restrict__ csr_src){
  int t = blockIdx.x*256 + threadIdx.x;
  if(t < NE/4){
    int4 d  = ((const int4*)(ei + NE))[t];
    int4 sv = ((const int4*)ei)[t];
    int p0 = atomicAdd(&cur[d.x],1); csr_src[row_ptr[d.x]+p0] = sv.x;
    int p1 = atomicAdd(&cur[d.y],1); csr_src[row_ptr[d.y]+p1] = sv.y;
    int p2 = atomicAdd(&cur[d.z],1); csr_src[row_ptr[d.z]+p2] = sv.z;
    int p3 = atomicAdd(&cur[d.w],1); csr_src[row_ptr[d.w]+p3] = sv.w;
  }
}

// ---------------- embed MLP + layer-0 PQR (fused) + cvec ----------------
__global__ __launch_bounds__(256) void embed_pqr_kernel(
    const float* __restrict__ x,
    const float* __restrict__ W1, const float* __restrict__ b1,
    const float* __restrict__ g1, const float* __restrict__ bb1,
    const float* __restrict__ W2, const float* __restrict__ b2,
    const float* __restrict__ g2, const float* __restrict__ bb2,
    const float* __restrict__ Wm, const float* __restrict__ bm,
    const float* __restrict__ Wu, const float* __restrict__ bu,
    const float* __restrict__ fb1, const float* __restrict__ fbng, const float* __restrict__ fbnb,
    float* __restrict__ h, float* __restrict__ pre,
    float* __restrict__ P, _Float16* __restrict__ Qh, float* __restrict__ R,
    float* __restrict__ cvec)
{
  int n = blockIdx.x*256 + threadIdx.x;
  const float rs = rsqrtf(1.0f + LN_EPS);
  if(n < 64) cvec[n] = fmaf(fb1[n], fbng[n]*rs, fbnb[n]);
  if(n >= NN) return;
  float xv[16];
  const float4* xp = (const float4*)(x + (size_t)n*16);
  #pragma unroll
  for(int i=0;i<4;i++){ float4 t=xp[i]; xv[4*i]=t.x; xv[4*i+1]=t.y; xv[4*i+2]=t.z; xv[4*i+3]=t.w; }
  float a1[64];
  #pragma unroll
  for(int j=0;j<64;j++) a1[j]=b1[j];
  #pragma unroll
  for(int k=0;k<16;k++){
    float xk=xv[k];
    #pragma unroll
    for(int j=0;j<64;j++) a1[j] += xk * W1[k*64+j];
  }
  #pragma unroll
  for(int j=0;j<64;j++) a1[j] = gelu_f(a1[j]*(g1[j]*rs) + bb1[j]);
  float hv[32];
  #pragma unroll
  for(int j=0;j<32;j++) hv[j]=b2[j];
  #pragma unroll
  for(int k=0;k<64;k++){
    float tk=a1[k];
    #pragma unroll
    for(int j=0;j<32;j++) hv[j] += tk * W2[k*32+j];
  }
  #pragma unroll
  for(int j=0;j<32;j++){
    hv[j] = gelu_f(hv[j]*(g2[j]*rs) + bb2[j]);
    h[(size_t)n*32+j]=hv[j]; pre[(size_t)n*32+j]=hv[j];
  }
  // PQR for layer 0
  float ap[32], aq[32], ar[32];
  #pragma unroll
  for(int j=0;j<32;j++){ ap[j]=bm[j]; aq[j]=0.f; ar[j]=bu[j]; }
  #pragma unroll
  for(int k=0;k<32;k++){
    float hk = hv[k];
    #pragma unroll
    for(int j=0;j<32;j++){
      ap[j] += hk * Wm[k*32+j];
      aq[j] += hk * Wm[(32+k)*32+j];
      ar[j] += hk * Wu[k*32+j];
    }
  }
  #pragma unroll
  for(int j=0;j<32;j++){ P[(size_t)n*32+j]=ap[j]; R[(size_t)n*32+j]=ar[j]; }
  half8* qo = (half8*)(Qh + (size_t)n*32);
  #pragma unroll
  for(int i=0;i<4;i++){
    half8 q;
    #pragma unroll
    for(int k=0;k<8;k++) q[k] = (_Float16)aq[8*i+k];
    qo[i] = q;
  }
}

// -------- message+aggregate: 16 lanes/node, 2-deep pipeline, reduce-scatter --------
__global__ __launch_bounds__(256) void msg_kernel(
    const float* __restrict__ P, const _Float16* __restrict__ Qh,
    const int* __restrict__ row_ptr, const int* __restrict__ csr_src,
    const float* __restrict__ mg, const float* __restrict__ mb,
    float* __restrict__ aggO)
{
  int tid = blockIdx.x*256 + threadIdx.x;
  int g = tid >> 4, s = tid & 15;
  bool valid = (g < NN);
  int n = valid ? g : 0;
  float p[32];
  const float4* pp = (const float4*)(P + (size_t)n*32);
  #pragma unroll
  for(int i=0;i<8;i++){ float4 t=pp[i]; p[4*i]=t.x; p[4*i+1]=t.y; p[4*i+2]=t.z; p[4*i+3]=t.w; }
  float agg[32];
  #pragma unroll
  for(int j=0;j<32;j++) agg[j]=0.f;
  int e0 = row_ptr[n], e1 = valid ? row_ptr[n+1] : e0;
  int e = e0 + s;
  int src0 = (e < e1) ? csr_src[e] : 0;
  const half8* q4 = (const half8*)(Qh + (size_t)src0*32);
  half8 qa0=q4[0], qa1=q4[1], qa2=q4[2], qa3=q4[3];
  while(e < e1){
    int e2 = e + 16;
    int src2 = (e2 < e1) ? csr_src[e2] : 0;
    const half8* q2 = (const half8*)(Qh + (size_t)src2*32);
    half8 qb0=q2[0], qb1=q2[1], qb2=q2[2], qb3=q2[3];   // prefetch next
    float v[32];
    #pragma unroll
    for(int k=0;k<8;k++){
      v[k]    = p[k]    + (float)qa0[k];
      v[8+k]  = p[8+k]  + (float)qa1[k];
      v[16+k] = p[16+k] + (float)qa2[k];
      v[24+k] = p[24+k] + (float)qa3[k];
    }
    float s0=0,s1=0,s2=0,s3=0;
    #pragma unroll
    for(int i=0;i<8;i++){ s0+=v[4*i]; s1+=v[4*i+1]; s2+=v[4*i+2]; s3+=v[4*i+3]; }
    float mean = ((s0+s1)+(s2+s3)) * 0.03125f;
    s0=s1=s2=s3=0.f;
    #pragma unroll
    for(int i=0;i<8;i++){
      float d0=v[4*i]-mean, d1=v[4*i+1]-mean, d2=v[4*i+2]-mean, d3=v[4*i+3]-mean;
      s0+=d0*d0; s1+=d1*d1; s2+=d2*d2; s3+=d3*d3;
      v[4*i]=d0; v[4*i+1]=d1; v[4*i+2]=d2; v[4*i+3]=d3;
    }
    float rstd = rsqrtf(((s0+s1)+(s2+s3))*0.03125f + LN_EPS);
    #pragma unroll
    for(int j=0;j<32;j++) agg[j] += gelu_f(v[j]*rstd*mg[j] + mb[j]);
    qa0=qb0; qa1=qb1; qa2=qb2; qa3=qb3;
    e = e2;
  }
  // reduce-scatter: 16 partial rows -> lane s holds summed features {2s, 2s+1}
  float r16[16];
  { int up = s & 8;
    #pragma unroll
    for(int j=0;j<16;j++){
      float mine   = up ? agg[16+j] : agg[j];
      float theirs = up ? agg[j]    : agg[16+j];
      r16[j] = mine + __shfl_xor(theirs, 8);
    } }
  float r8[8];
  { int up = s & 4;
    #pragma unroll
    for(int j=0;j<8;j++){
      float mine   = up ? r16[8+j] : r16[j];
      float theirs = up ? r16[j]   : r16[8+j];
      r8[j] = mine + __shfl_xor(theirs, 4);
    } }
  float r4[4];
  { int up = s & 2;
    #pragma unroll
    for(int j=0;j<4;j++){
      float mine   = up ? r8[4+j] : r8[j];
      float theirs = up ? r8[j]   : r8[4+j];
      r4[j] = mine + __shfl_xor(theirs, 2);
    } }
  float r2[2];
  { int up = s & 1;
    #pragma unroll
    for(int j=0;j<2;j++){
      float mine   = up ? r4[2+j] : r4[j];
      float theirs = up ? r4[j]   : r4[2+j];
      r2[j] = mine + __shfl_xor(theirs, 1);
    } }
  if(valid){
    float2 st; st.x=r2[0]; st.y=r2[1];
    ((float2*)(aggO + (size_t)n*32))[s] = st;
  }
}

// -------- update MLP + next-layer PQR (fused, node per lane) --------
__global__ __launch_bounds__(256) void upd_pqr_kernel(
    const float* __restrict__ aggI, const float* __restrict__ Rio,
    const float* __restrict__ Ub,
    const float* __restrict__ ug, const float* __restrict__ ub,
    const float* __restrict__ Wm2, const float* __restrict__ bm2,
    const float* __restrict__ Wu2, const float* __restrict__ bu2,
    float* __restrict__ h,
    float* __restrict__ P, _Float16* __restrict__ Qh, float* __restrict__ Rout)
{
  int n = blockIdx.x*256 + threadIdx.x;
  if(n >= NN) return;
  float agg[32], u[32];
  const float4* ap4 = (const float4*)(aggI + (size_t)n*32);
  const float4* rp4 = (const float4*)(Rio + (size_t)n*32);
  #pragma unroll
  for(int i=0;i<8;i++){ float4 t=ap4[i]; agg[4*i]=t.x; agg[4*i+1]=t.y; agg[4*i+2]=t.z; agg[4*i+3]=t.w; }
  #pragma unroll
  for(int i=0;i<8;i++){ float4 t=rp4[i]; u[4*i]=t.x; u[4*i+1]=t.y; u[4*i+2]=t.z; u[4*i+3]=t.w; }
  #pragma unroll
  for(int k=0;k<32;k++){
    float a = agg[k];
    #pragma unroll
    for(int j=0;j<32;j++) u[j] += a * Ub[k*32+j];
  }
  float s0=0,s1=0,s2=0,s3=0;
  #pragma unroll
  for(int i=0;i<8;i++){ s0+=u[4*i]; s1+=u[4*i+1]; s2+=u[4*i+2]; s3+=u[4*i+3]; }
  float mean = ((s0+s1)+(s2+s3)) * 0.03125f;
  s0=s1=s2=s3=0.f;
  #pragma unroll
  for(int i=0;i<8;i++){
    float d0=u[4*i]-mean, d1=u[4*i+1]-mean, d2=u[4*i+2]-mean, d3=u[4*i+3]-mean;
    s0+=d0*d0; s1+=d1*d1; s2+=d2*d2; s3+=d3*d3;
    u[4*i]=d0; u[4*i+1]=d1; u[4*i+2]=d2; u[4*i+3]=d3;
  }
  float rstd = rsqrtf(((s0+s1)+(s2+s3))*0.03125f + LN_EPS);
  float hv[32];
  const float4* hp4 = (const float4*)(h + (size_t)n*32);
  #pragma unroll
  for(int i=0;i<8;i++){ float4 t=hp4[i]; hv[4*i]=t.x; hv[4*i+1]=t.y; hv[4*i+2]=t.z; hv[4*i+3]=t.w; }
  #pragma unroll
  for(int j=0;j<32;j++) hv[j] += gelu_f(u[j]*rstd*ug[j] + ub[j]);
  float4* ho = (float4*)(h + (size_t)n*32);
  #pragma unroll
  for(int i=0;i<8;i++){ float4 t; t.x=hv[4*i]; t.y=hv[4*i+1]; t.z=hv[4*i+2]; t.w=hv[4*i+3]; ho[i]=t; }
  // PQR for next layer
  float pq[32], qq[32], rr[32];
  #pragma unroll
  for(int j=0;j<32;j++){ pq[j]=bm2[j]; qq[j]=0.f; rr[j]=bu2[j]; }
  #pragma unroll
  for(int k=0;k<32;k++){
    float hk = hv[k];
    #pragma unroll
    for(int j=0;j<32;j++){
      pq[j] += hk * Wm2[k*32+j];
      qq[j] += hk * Wm2[(32+k)*32+j];
      rr[j] += hk * Wu2[k*32+j];
    }
  }
  #pragma unroll
  for(int j=0;j<32;j++){ P[(size_t)n*32+j]=pq[j]; Rout[(size_t)n*32+j]=rr[j]; }
  half8* qo = (half8*)(Qh + (size_t)n*32);
  #pragma unroll
  for(int i=0;i<4;i++){
    half8 q;
    #pragma unroll
    for(int k=0;k<8;k++) q[k] = (_Float16)qq[8*i+k];
    qo[i] = q;
  }
}

// -------- last-layer update + final node matmul y = ((h+pre)@fW1)*bn (fp16) --------
__global__ __launch_bounds__(256) void upd_fin_kernel(
    const float* __restrict__ aggI, const float* __restrict__ Rio,
    const float* __restrict__ Ub,
    const float* __restrict__ ug, const float* __restrict__ ub,
    const float* __restrict__ h, const float* __restrict__ pre,
    const float* __restrict__ fW1, const float* __restrict__ fbng,
    _Float16* __restrict__ y)
{
  int n = blockIdx.x*256 + threadIdx.x;
  if(n >= NN) return;
  const float rs = rsqrtf(1.0f + LN_EPS);
  float agg[32], u[32];
  const float4* ap4 = (const float4*)(aggI + (size_t)n*32);
  const float4* rp4 = (const float4*)(Rio + (size_t)n*32);
  #pragma unroll
  for(int i=0;i<8;i++){ float4 t=ap4[i]; agg[4*i]=t.x; agg[4*i+1]=t.y; agg[4*i+2]=t.z; agg[4*i+3]=t.w; }
  #pragma unroll
  for(int i=0;i<8;i++){ float4 t=rp4[i]; u[4*i]=t.x; u[4*i+1]=t.y; u[4*i+2]=t.z; u[4*i+3]=t.w; }
  #pragma unroll
  for(int k=0;k<32;k++){
    float a = agg[k];
    #pragma unroll
    for(int j=0;j<32;j++) u[j] += a * Ub[k*32+j];
  }
  float s0=0,s1=0,s2=0,s3=0;
  #pragma unroll
  for(int i=0;i<8;i++){ s0+=u[4*i]; s1+=u[4*i+1]; s2+=u[4*i+2]; s3+=u[4*i+3]; }
  float mean = ((s0+s1)+(s2+s3)) * 0.03125f;
  s0=s1=s2=s3=0.f;
  #pragma unroll
  for(int i=0;i<8;i++){
    float d0=u[4*i]-mean, d1=u[4*i+1]-mean, d2=u[4*i+2]-mean, d3=u[4*i+3]-mean;
    s0+=d0*d0; s1+=d1*d1; s2+=d2*d2; s3+=d3*d3;
    u[4*i]=d0; u[4*i+1]=d1; u[4*i+2]=d2; u[4*i+3]=d3;
  }
  float rstd = rsqrtf(((s0+s1)+(s2+s3))*0.03125f + LN_EPS);
  float hv[32];
  const float4* hp4 = (const float4*)(h + (size_t)n*32);
  const float4* pp4 = (const float4*)(pre + (size_t)n*32);
  #pragma unroll
  for(int i=0;i<8;i++){ float4 t=hp4[i]; hv[4*i]=t.x; hv[4*i+1]=t.y; hv[4*i+2]=t.z; hv[4*i+3]=t.w; }
  #pragma unroll
  for(int j=0;j<32;j++) hv[j] += gelu_f(u[j]*rstd*ug[j] + ub[j]);
  #pragma unroll
  for(int i=0;i<8;i++){ float4 t=pp4[i]; hv[4*i]+=t.x; hv[4*i+1]+=t.y; hv[4*i+2]+=t.z; hv[4*i+3]+=t.w; }
  float acc[64];
  #pragma unroll
  for(int j=0;j<64;j++) acc[j]=0.f;
  #pragma unroll
  for(int k=0;k<32;k++){
    float hk = hv[k];
    #pragma unroll
    for(int j=0;j<64;j++) acc[j] += hk * fW1[k*64+j];
  }
  half8* yo = (half8*)(y + (size_t)n*64);
  #pragma unroll
  for(int i=0;i<8;i++){
    half8 q;
    #pragma unroll
    for(int k=0;k<8;k++) q[k] = (_Float16)(acc[8*i+k] * (fbng[8*i+k]*rs));
    yo[i] = q;
  }
}

// ---------------- final per-edge: 2 edges per thread, interleaved ----------------
__global__ __launch_bounds__(256) void final_kernel(
    const _Float16* __restrict__ y, const int* __restrict__ ei,
    const float* __restrict__ cvec,
    const float* __restrict__ W2, const float* __restrict__ b2,
    float* __restrict__ out)
{
  int t = blockIdx.x*256 + threadIdx.x;
  if(t >= NE/2) return;
  int eA = t, eB = t + NE/2;
  int sA = ei[eA], dA = ei[NE+eA];
  int sB = ei[eB], dB = ei[NE+eB];
  const half8* pdA = (const half8*)(y + (size_t)dA*64);
  const half8* psA = (const half8*)(y + (size_t)sA*64);
  const half8* pdB = (const half8*)(y + (size_t)dB*64);
  const half8* psB = (const half8*)(y + (size_t)sB*64);
  float oA0=b2[0], oA1=b2[1], oA2=b2[2];
  float oB0=oA0, oB1=oA1, oB2=oA2;
  #pragma unroll
  for(int i=0;i<8;i++){
    half8 aA=pdA[i], cA=psA[i], aB=pdB[i], cB=psB[i];
    #pragma unroll
    for(int k=0;k<8;k++){
      int j = 8*i+k;
      float tA = gelu_f(((float)aA[k]-(float)cA[k]) + cvec[j]);
      float tB = gelu_f(((float)aB[k]-(float)cB[k]) + cvec[j]);
      float w0=W2[j*3+0], w1=W2[j*3+1], w2=W2[j*3+2];
      oA0 += tA*w0; oA1 += tA*w1; oA2 += tA*w2;
      oB0 += tB*w0; oB1 += tB*w1; oB2 += tB*w2;
    }
  }
  out[(size_t)eA*3+0]=oA0; out[(size_t)eA*3+1]=oA1; out[(size_t)eA*3+2]=oA2;
  out[(size_t)eB*3+0]=oB0; out[(size_t)eB*3+1]=oB1; out[(size_t)eB*3+2]=oB2;
}

extern "C" void kernel_launch(void* const* d_in, const int* in_sizes, int n_in,
                              void* d_out, int out_size, void* d_ws, size_t ws_size,
                              hipStream_t stream)
{
  (void)in_sizes; (void)n_in; (void)out_size; (void)ws_size;
  const float* x     = (const float*)d_in[0];
  const int*   ei    = (const int*)d_in[1];
  const float* eW1   = (const float*)d_in[2];
  const float* eb1   = (const float*)d_in[3];
  const float* ebn1g = (const float*)d_in[4];
  const float* ebn1b = (const float*)d_in[5];
  const float* eW2   = (const float*)d_in[6];
  const float* eb2   = (const float*)d_in[7];
  const float* ebn2g = (const float*)d_in[8];
  const float* ebn2b = (const float*)d_in[9];
  const float* msgW  = (const float*)d_in[10];
  const float* msgb  = (const float*)d_in[11];
  const float* msglng= (const float*)d_in[12];
  const float* msglnb= (const float*)d_in[13];
  const float* updW  = (const float*)d_in[14];
  const float* updb  = (const float*)d_in[15];
  const float* updlng= (const float*)d_in[16];
  const float* updlnb= (const float*)d_in[17];
  const float* fW1   = (const float*)d_in[18];
  const float* fb1   = (const float*)d_in[19];
  const float* fbng  = (const float*)d_in[20];
  const float* fbnb  = (const float*)d_in[21];
  const float* fW2   = (const float*)d_in[22];
  const float* fb2   = (const float*)d_in[23];
  float* out = (float*)d_out;

  // workspace: h, pre, P, R, agg (each NN*32 f32), Qh (NN*32 f16), ints
  float* f   = (float*)d_ws;
  float* h   = f;
  float* pre = f + 1*(size_t)NN*32;
  float* P   = f + 2*(size_t)NN*32;
  float* R   = f + 3*(size_t)NN*32;
  float* agg = f + 4*(size_t)NN*32;
  _Float16* Qh = (_Float16*)(f + 5*(size_t)NN*32);   // NN*32 halves
  _Float16* y  = (_Float16*)P;                        // NN*64 halves aliases P (dead then)
  int* ip      = (int*)(f + 5*(size_t)NN*32 + (size_t)NN*16);
  int* row_ptr = ip;            // NN+1
  int* cnt     = ip + NN + 1;   // NN (dead after fill -> reused for cvec)
  int* csr     = ip + 2*NN + 1; // NE
  float* cvec  = (float*)cnt;   // 64 floats, written by embed_pqr (after fill)

  hipMemsetAsync(cnt, 0, NN*sizeof(int), stream);
  hist_kernel<<<(NE/4+255)/256, 256, 0, stream>>>(ei, cnt);
  scan_kernel<<<1, 1024, 0, stream>>>(cnt, row_ptr);
  hipMemsetAsync(cnt, 0, NN*sizeof(int), stream);
  fill_kernel<<<(NE/4+255)/256, 256, 0, stream>>>(ei, row_ptr, cnt, csr);

  embed_pqr_kernel<<<(NN+255)/256, 256, 0, stream>>>(x, eW1, eb1, ebn1g, ebn1b,
      eW2, eb2, ebn2g, ebn2b,
      msgW, msgb, updW, updb,
      fb1, fbng, fbnb,
      h, pre, P, Qh, R, cvec);

  for(int l=0; l<3; l++){
    msg_kernel<<<((NN*16)+255)/256, 256, 0, stream>>>(P, Qh, row_ptr, csr,
        msglng + l*32, msglnb + l*32, agg);
    if(l < 2){
      upd_pqr_kernel<<<(NN+255)/256, 256, 0, stream>>>(agg, R,
          updW + l*2048 + 1024, updlng + l*32, updlnb + l*32,
          msgW + (l+1)*2048, msgb + (l+1)*32,
          updW + (l+1)*2048, updb + (l+1)*32,
          h, P, Qh, R);
    } else {
      upd_fin_kernel<<<(NN+255)/256, 256, 0, stream>>>(agg, R,
          updW + l*2048 + 1024, updlng + l*32, updlnb + l*32,
          h, pre, fW1, fbng, y);
    }
  }

  final_kernel<<<((NE/2)+255)/256, 256, 0, stream>>>(y, ei, cvec, fW2, fb2, out);
}

// Round 4
// 668.028 us; speedup vs baseline: 2.1889x; 1.0475x over previous
//
#include <hip/hip_runtime.h>

#define NN 50000
#define NE 1600000
constexpr float LN_EPS = 1e-5f;

typedef _Float16 half8 __attribute__((ext_vector_type(8)));

// Branchless erf-GELU: Abramowitz-Stegun 7.1.26, |eps| <= 1.5e-7
__device__ __forceinline__ float gelu_f(float x){
  float ax = fabsf(x) * 0.70710678118654752440f;
  float t  = __builtin_amdgcn_rcpf(fmaf(0.3275911f, ax, 1.0f));
  float e  = __expf(-ax*ax);
  float p  = t*fmaf(t, fmaf(t, fmaf(t, fmaf(t, 1.061405429f, -1.453152027f),
                                    1.421413741f), -0.284496736f), 0.254829592f);
  float er = fmaf(-p, e, 1.0f);
  return 0.5f * x * (1.0f + copysignf(er, x));
}

// ---------------- CSR build ----------------
__global__ __launch_bounds__(256) void hist_kernel(const int* __restrict__ ei, int* __restrict__ cnt){
  int t = blockIdx.x*256 + threadIdx.x;
  if(t < NE/4){
    int4 d = ((const int4*)(ei + NE))[t];
    atomicAdd(&cnt[d.x],1); atomicAdd(&cnt[d.y],1);
    atomicAdd(&cnt[d.z],1); atomicAdd(&cnt[d.w],1);
  }
}

#define CHUNK 52  // 1024*52 = 53248 >= 50000
__global__ __launch_bounds__(1024) void scan_kernel(const int* __restrict__ deg, int* __restrict__ row_ptr){
  __shared__ int sums[1024];
  int t = threadIdx.x;
  int base = t*CHUNK;
  int4 v[13];
  int ssum = 0;
  #pragma unroll
  for(int i=0;i<13;i++){
    int idx = base + 4*i;
    if(idx + 3 < NN){
      v[i] = ((const int4*)deg)[(base>>2)+i];
    } else {
      v[i].x = (idx+0<NN)?deg[idx+0]:0; v[i].y = (idx+1<NN)?deg[idx+1]:0;
      v[i].z = (idx+2<NN)?deg[idx+2]:0; v[i].w = (idx+3<NN)?deg[idx+3]:0;
    }
    ssum += v[i].x + v[i].y + v[i].z + v[i].w;
  }
  sums[t]=ssum;
  __syncthreads();
  for(int off=1; off<1024; off<<=1){
    int vv = (t>=off) ? sums[t-off] : 0;
    __syncthreads();
    sums[t] += vv;
    __syncthreads();
  }
  int run = (t>0) ? sums[t-1] : 0;
  #pragma unroll
  for(int i=0;i<13;i++){
    int idx = base + 4*i;
    int4 o;
    o.x = run; run += v[i].x;
    o.y = run; run += v[i].y;
    o.z = run; run += v[i].z;
    o.w = run; run += v[i].w;
    if(idx + 3 < NN){
      ((int4*)row_ptr)[(base>>2)+i] = o;
    } else {
      if(idx+0<NN) row_ptr[idx+0]=o.x;
      if(idx+1<NN) row_ptr[idx+1]=o.y;
      if(idx+2<NN) row_ptr[idx+2]=o.z;
      if(idx+3<NN) row_ptr[idx+3]=o.w;
    }
  }
  if(t==1023) row_ptr[NN] = sums[1023];
}

__global__ __launch_bounds__(256) void fill_kernel(const int* __restrict__ ei,
    const int* __restrict__ row_ptr, int* __restrict__ cur, int* __restrict__ csr_src){
  int t = blockIdx.x*256 + threadIdx.x;
  if(t < NE/4){
    int4 d  = ((const int4*)(ei + NE))[t];
    int4 sv = ((const int4*)ei)[t];
    int p0 = atomicAdd(&cur[d.x],1); csr_src[row_ptr[d.x]+p0] = sv.x;
    int p1 = atomicAdd(&cur[d.y],1); csr_src[row_ptr[d.y]+p1] = sv.y;
    int p2 = atomicAdd(&cur[d.z],1); csr_src[row_ptr[d.z]+p2] = sv.z;
    int p3 = atomicAdd(&cur[d.w],1); csr_src[row_ptr[d.w]+p3] = sv.w;
  }
}

// ---------------- embed MLP + layer-0 PQR (fused) + cvec ----------------
__global__ __launch_bounds__(256) void embed_pqr_kernel(
    const float* __restrict__ x,
    const float* __restrict__ W1, const float* __restrict__ b1,
    const float* __restrict__ g1, const float* __restrict__ bb1,
    const float* __restrict__ W2, const float* __restrict__ b2,
    const float* __restrict__ g2, const float* __restrict__ bb2,
    const float* __restrict__ Wm, const float* __restrict__ bm,
    const float* __restrict__ Wu, const float* __restrict__ bu,
    const float* __restrict__ fb1, const float* __restrict__ fbng, const float* __restrict__ fbnb,
    float* __restrict__ h, float* __restrict__ pre,
    float* __restrict__ P, _Float16* __restrict__ Qh, float* __restrict__ R,
    float* __restrict__ cvec)
{
  int n = blockIdx.x*256 + threadIdx.x;
  const float rs = rsqrtf(1.0f + LN_EPS);
  if(n < 64) cvec[n] = fmaf(fb1[n], fbng[n]*rs, fbnb[n]);
  if(n >= NN) return;
  float xv[16];
  const float4* xp = (const float4*)(x + (size_t)n*16);
  #pragma unroll
  for(int i=0;i<4;i++){ float4 t=xp[i]; xv[4*i]=t.x; xv[4*i+1]=t.y; xv[4*i+2]=t.z; xv[4*i+3]=t.w; }
  float a1[64];
  #pragma unroll
  for(int j=0;j<64;j++) a1[j]=b1[j];
  #pragma unroll
  for(int k=0;k<16;k++){
    float xk=xv[k];
    #pragma unroll
    for(int j=0;j<64;j++) a1[j] += xk * W1[k*64+j];
  }
  #pragma unroll
  for(int j=0;j<64;j++) a1[j] = gelu_f(a1[j]*(g1[j]*rs) + bb1[j]);
  float hv[32];
  #pragma unroll
  for(int j=0;j<32;j++) hv[j]=b2[j];
  #pragma unroll
  for(int k=0;k<64;k++){
    float tk=a1[k];
    #pragma unroll
    for(int j=0;j<32;j++) hv[j] += tk * W2[k*32+j];
  }
  #pragma unroll
  for(int j=0;j<32;j++){
    hv[j] = gelu_f(hv[j]*(g2[j]*rs) + bb2[j]);
    h[(size_t)n*32+j]=hv[j]; pre[(size_t)n*32+j]=hv[j];
  }
  // PQR for layer 0
  float ap[32], aq[32], ar[32];
  #pragma unroll
  for(int j=0;j<32;j++){ ap[j]=bm[j]; aq[j]=0.f; ar[j]=bu[j]; }
  #pragma unroll
  for(int k=0;k<32;k++){
    float hk = hv[k];
    #pragma unroll
    for(int j=0;j<32;j++){
      ap[j] += hk * Wm[k*32+j];
      aq[j] += hk * Wm[(32+k)*32+j];
      ar[j] += hk * Wu[k*32+j];
    }
  }
  #pragma unroll
  for(int j=0;j<32;j++){ P[(size_t)n*32+j]=ap[j]; R[(size_t)n*32+j]=ar[j]; }
  half8* qo = (half8*)(Qh + (size_t)n*32);
  #pragma unroll
  for(int i=0;i<4;i++){
    half8 q;
    #pragma unroll
    for(int k=0;k<8;k++) q[k] = (_Float16)aq[8*i+k];
    qo[i] = q;
  }
}

// -------- message+aggregate: 16 lanes/node, 2-deep pipeline, reduce-scatter --------
__global__ __launch_bounds__(256) void msg_kernel(
    const float* __restrict__ P, const _Float16* __restrict__ Qh,
    const int* __restrict__ row_ptr, const int* __restrict__ csr_src,
    const float* __restrict__ mg, const float* __restrict__ mb,
    float* __restrict__ aggO)
{
  int tid = blockIdx.x*256 + threadIdx.x;
  int g = tid >> 4, s = tid & 15;
  bool valid = (g < NN);
  int n = valid ? g : 0;
  float p[32];
  const float4* pp = (const float4*)(P + (size_t)n*32);
  #pragma unroll
  for(int i=0;i<8;i++){ float4 t=pp[i]; p[4*i]=t.x; p[4*i+1]=t.y; p[4*i+2]=t.z; p[4*i+3]=t.w; }
  float agg[32];
  #pragma unroll
  for(int j=0;j<32;j++) agg[j]=0.f;
  int e0 = row_ptr[n], e1 = valid ? row_ptr[n+1] : e0;
  int e = e0 + s;
  int src0 = (e < e1) ? csr_src[e] : 0;
  const half8* q4 = (const half8*)(Qh + (size_t)src0*32);
  half8 qa0=q4[0], qa1=q4[1], qa2=q4[2], qa3=q4[3];
  while(e < e1){
    int e2 = e + 16;
    int src2 = (e2 < e1) ? csr_src[e2] : 0;
    const half8* q2 = (const half8*)(Qh + (size_t)src2*32);
    half8 qb0=q2[0], qb1=q2[1], qb2=q2[2], qb3=q2[3];   // prefetch next
    float v[32];
    #pragma unroll
    for(int k=0;k<8;k++){
      v[k]    = p[k]    + (float)qa0[k];
      v[8+k]  = p[8+k]  + (float)qa1[k];
      v[16+k] = p[16+k] + (float)qa2[k];
      v[24+k] = p[24+k] + (float)qa3[k];
    }
    float s0=0,s1=0,s2=0,s3=0;
    #pragma unroll
    for(int i=0;i<8;i++){ s0+=v[4*i]; s1+=v[4*i+1]; s2+=v[4*i+2]; s3+=v[4*i+3]; }
    float mean = ((s0+s1)+(s2+s3)) * 0.03125f;
    s0=s1=s2=s3=0.f;
    #pragma unroll
    for(int i=0;i<8;i++){
      float d0=v[4*i]-mean, d1=v[4*i+1]-mean, d2=v[4*i+2]-mean, d3=v[4*i+3]-mean;
      s0+=d0*d0; s1+=d1*d1; s2+=d2*d2; s3+=d3*d3;
      v[4*i]=d0; v[4*i+1]=d1; v[4*i+2]=d2; v[4*i+3]=d3;
    }
    float rstd = rsqrtf(((s0+s1)+(s2+s3))*0.03125f + LN_EPS);
    #pragma unroll
    for(int j=0;j<32;j++) agg[j] += gelu_f(v[j]*rstd*mg[j] + mb[j]);
    qa0=qb0; qa1=qb1; qa2=qb2; qa3=qb3;
    e = e2;
  }
  // reduce-scatter: 16 partial rows -> lane s holds summed features {2s, 2s+1}
  float r16[16];
  { int up = s & 8;
    #pragma unroll
    for(int j=0;j<16;j++){
      float mine   = up ? agg[16+j] : agg[j];
      float theirs = up ? agg[j]    : agg[16+j];
      r16[j] = mine + __shfl_xor(theirs, 8);
    } }
  float r8[8];
  { int up = s & 4;
    #pragma unroll
    for(int j=0;j<8;j++){
      float mine   = up ? r16[8+j] : r16[j];
      float theirs = up ? r16[j]   : r16[8+j];
      r8[j] = mine + __shfl_xor(theirs, 4);
    } }
  float r4[4];
  { int up = s & 2;
    #pragma unroll
    for(int j=0;j<4;j++){
      float mine   = up ? r8[4+j] : r8[j];
      float theirs = up ? r8[j]   : r8[4+j];
      r4[j] = mine + __shfl_xor(theirs, 2);
    } }
  float r2[2];
  { int up = s & 1;
    #pragma unroll
    for(int j=0;j<2;j++){
      float mine   = up ? r4[2+j] : r4[j];
      float theirs = up ? r4[j]   : r4[2+j];
      r2[j] = mine + __shfl_xor(theirs, 1);
    } }
  if(valid){
    float2 st; st.x=r2[0]; st.y=r2[1];
    ((float2*)(aggO + (size_t)n*32))[s] = st;
  }
}

// -------- update MLP + next-layer PQR (fused, node per lane) --------
__global__ __launch_bounds__(256) void upd_pqr_kernel(
    const float* __restrict__ aggI, const float* __restrict__ Rio,
    const float* __restrict__ Ub,
    const float* __restrict__ ug, const float* __restrict__ ub,
    const float* __restrict__ Wm2, const float* __restrict__ bm2,
    const float* __restrict__ Wu2, const float* __restrict__ bu2,
    float* __restrict__ h,
    float* __restrict__ P, _Float16* __restrict__ Qh, float* __restrict__ Rout)
{
  int n = blockIdx.x*256 + threadIdx.x;
  if(n >= NN) return;
  float agg[32], u[32];
  const float4* ap4 = (const float4*)(aggI + (size_t)n*32);
  const float4* rp4 = (const float4*)(Rio + (size_t)n*32);
  #pragma unroll
  for(int i=0;i<8;i++){ float4 t=ap4[i]; agg[4*i]=t.x; agg[4*i+1]=t.y; agg[4*i+2]=t.z; agg[4*i+3]=t.w; }
  #pragma unroll
  for(int i=0;i<8;i++){ float4 t=rp4[i]; u[4*i]=t.x; u[4*i+1]=t.y; u[4*i+2]=t.z; u[4*i+3]=t.w; }
  #pragma unroll
  for(int k=0;k<32;k++){
    float a = agg[k];
    #pragma unroll
    for(int j=0;j<32;j++) u[j] += a * Ub[k*32+j];
  }
  float s0=0,s1=0,s2=0,s3=0;
  #pragma unroll
  for(int i=0;i<8;i++){ s0+=u[4*i]; s1+=u[4*i+1]; s2+=u[4*i+2]; s3+=u[4*i+3]; }
  float mean = ((s0+s1)+(s2+s3)) * 0.03125f;
  s0=s1=s2=s3=0.f;
  #pragma unroll
  for(int i=0;i<8;i++){
    float d0=u[4*i]-mean, d1=u[4*i+1]-mean, d2=u[4*i+2]-mean, d3=u[4*i+3]-mean;
    s0+=d0*d0; s1+=d1*d1; s2+=d2*d2; s3+=d3*d3;
    u[4*i]=d0; u[4*i+1]=d1; u[4*i+2]=d2; u[4*i+3]=d3;
  }
  float rstd = rsqrtf(((s0+s1)+(s2+s3))*0.03125f + LN_EPS);
  float hv[32];
  const float4* hp4 = (const float4*)(h + (size_t)n*32);
  #pragma unroll
  for(int i=0;i<8;i++){ float4 t=hp4[i]; hv[4*i]=t.x; hv[4*i+1]=t.y; hv[4*i+2]=t.z; hv[4*i+3]=t.w; }
  #pragma unroll
  for(int j=0;j<32;j++) hv[j] += gelu_f(u[j]*rstd*ug[j] + ub[j]);
  float4* ho = (float4*)(h + (size_t)n*32);
  #pragma unroll
  for(int i=0;i<8;i++){ float4 t; t.x=hv[4*i]; t.y=hv[4*i+1]; t.z=hv[4*i+2]; t.w=hv[4*i+3]; ho[i]=t; }
  // PQR for next layer
  float pq[32], qq[32], rr[32];
  #pragma unroll
  for(int j=0;j<32;j++){ pq[j]=bm2[j]; qq[j]=0.f; rr[j]=bu2[j]; }
  #pragma unroll
  for(int k=0;k<32;k++){
    float hk = hv[k];
    #pragma unroll
    for(int j=0;j<32;j++){
      pq[j] += hk * Wm2[k*32+j];
      qq[j] += hk * Wm2[(32+k)*32+j];
      rr[j] += hk * Wu2[k*32+j];
    }
  }
  #pragma unroll
  for(int j=0;j<32;j++){ P[(size_t)n*32+j]=pq[j]; Rout[(size_t)n*32+j]=rr[j]; }
  half8* qo = (half8*)(Qh + (size_t)n*32);
  #pragma unroll
  for(int i=0;i<4;i++){
    half8 q;
    #pragma unroll
    for(int k=0;k<8;k++) q[k] = (_Float16)qq[8*i+k];
    qo[i] = q;
  }
}

// -------- last-layer update + final node matmul, split-half fp16 outputs --------
__global__ __launch_bounds__(256) void upd_fin_kernel(
    const float* __restrict__ aggI, const float* __restrict__ Rio,
    const float* __restrict__ Ub,
    const float* __restrict__ ug, const float* __restrict__ ub,
    const float* __restrict__ h, const float* __restrict__ pre,
    const float* __restrict__ fW1, const float* __restrict__ fbng,
    _Float16* __restrict__ y1, _Float16* __restrict__ y2)
{
  int n = blockIdx.x*256 + threadIdx.x;
  if(n >= NN) return;
  const float rs = rsqrtf(1.0f + LN_EPS);
  float agg[32], u[32];
  const float4* ap4 = (const float4*)(aggI + (size_t)n*32);
  const float4* rp4 = (const float4*)(Rio + (size_t)n*32);
  #pragma unroll
  for(int i=0;i<8;i++){ float4 t=ap4[i]; agg[4*i]=t.x; agg[4*i+1]=t.y; agg[4*i+2]=t.z; agg[4*i+3]=t.w; }
  #pragma unroll
  for(int i=0;i<8;i++){ float4 t=rp4[i]; u[4*i]=t.x; u[4*i+1]=t.y; u[4*i+2]=t.z; u[4*i+3]=t.w; }
  #pragma unroll
  for(int k=0;k<32;k++){
    float a = agg[k];
    #pragma unroll
    for(int j=0;j<32;j++) u[j] += a * Ub[k*32+j];
  }
  float s0=0,s1=0,s2=0,s3=0;
  #pragma unroll
  for(int i=0;i<8;i++){ s0+=u[4*i]; s1+=u[4*i+1]; s2+=u[4*i+2]; s3+=u[4*i+3]; }
  float mean = ((s0+s1)+(s2+s3)) * 0.03125f;
  s0=s1=s2=s3=0.f;
  #pragma unroll
  for(int i=0;i<8;i++){
    float d0=u[4*i]-mean, d1=u[4*i+1]-mean, d2=u[4*i+2]-mean, d3=u[4*i+3]-mean;
    s0+=d0*d0; s1+=d1*d1; s2+=d2*d2; s3+=d3*d3;
    u[4*i]=d0; u[4*i+1]=d1; u[4*i+2]=d2; u[4*i+3]=d3;
  }
  float rstd = rsqrtf(((s0+s1)+(s2+s3))*0.03125f + LN_EPS);
  float hv[32];
  const float4* hp4 = (const float4*)(h + (size_t)n*32);
  const float4* pp4 = (const float4*)(pre + (size_t)n*32);
  #pragma unroll
  for(int i=0;i<8;i++){ float4 t=hp4[i]; hv[4*i]=t.x; hv[4*i+1]=t.y; hv[4*i+2]=t.z; hv[4*i+3]=t.w; }
  #pragma unroll
  for(int j=0;j<32;j++) hv[j] += gelu_f(u[j]*rstd*ug[j] + ub[j]);
  #pragma unroll
  for(int i=0;i<8;i++){ float4 t=pp4[i]; hv[4*i]+=t.x; hv[4*i+1]+=t.y; hv[4*i+2]+=t.z; hv[4*i+3]+=t.w; }
  float acc[64];
  #pragma unroll
  for(int j=0;j<64;j++) acc[j]=0.f;
  #pragma unroll
  for(int k=0;k<32;k++){
    float hk = hv[k];
    #pragma unroll
    for(int j=0;j<64;j++) acc[j] += hk * fW1[k*64+j];
  }
  half8* yo1 = (half8*)(y1 + (size_t)n*32);
  half8* yo2 = (half8*)(y2 + (size_t)n*32);
  #pragma unroll
  for(int i=0;i<4;i++){
    half8 qa, qb;
    #pragma unroll
    for(int k=0;k<8;k++){
      qa[k] = (_Float16)(acc[8*i+k]      * (fbng[8*i+k]*rs));
      qb[k] = (_Float16)(acc[32+8*i+k]   * (fbng[32+8*i+k]*rs));
    }
    yo1[i] = qa; yo2[i] = qb;
  }
}

// ---------------- final per-edge, feature-split passes (y-half is L2-resident) ----------------
__global__ __launch_bounds__(256) void finalA_kernel(
    const _Float16* __restrict__ y, const int* __restrict__ ei,
    const float* __restrict__ cvec,
    const float* __restrict__ W2, const float* __restrict__ b2,
    float* __restrict__ out)
{
  int e = blockIdx.x*256 + threadIdx.x;
  if(e >= NE) return;
  int s = __builtin_nontemporal_load(ei + e);
  int d = __builtin_nontemporal_load(ei + NE + e);
  const half8* pd = (const half8*)(y + (size_t)d*32);
  const half8* ps = (const half8*)(y + (size_t)s*32);
  float o0=b2[0], o1=b2[1], o2=b2[2];
  #pragma unroll
  for(int i=0;i<4;i++){
    half8 a8=pd[i], c8=ps[i];
    #pragma unroll
    for(int k=0;k<8;k++){
      int j = 8*i+k;
      float t = gelu_f(((float)a8[k]-(float)c8[k]) + cvec[j]);
      o0 += t*W2[j*3+0]; o1 += t*W2[j*3+1]; o2 += t*W2[j*3+2];
    }
  }
  __builtin_nontemporal_store(o0, out + (size_t)e*3+0);
  __builtin_nontemporal_store(o1, out + (size_t)e*3+1);
  __builtin_nontemporal_store(o2, out + (size_t)e*3+2);
}

__global__ __launch_bounds__(256) void finalB_kernel(
    const _Float16* __restrict__ y, const int* __restrict__ ei,
    const float* __restrict__ cvec,   // cvec+32
    const float* __restrict__ W2,     // W2+96 (rows 32..63)
    float* __restrict__ out)
{
  int e = blockIdx.x*256 + threadIdx.x;
  if(e >= NE) return;
  int s = __builtin_nontemporal_load(ei + e);
  int d = __builtin_nontemporal_load(ei + NE + e);
  const half8* pd = (const half8*)(y + (size_t)d*32);
  const half8* ps = (const half8*)(y + (size_t)s*32);
  float o0 = __builtin_nontemporal_load(out + (size_t)e*3+0);
  float o1 = __builtin_nontemporal_load(out + (size_t)e*3+1);
  float o2 = __builtin_nontemporal_load(out + (size_t)e*3+2);
  #pragma unroll
  for(int i=0;i<4;i++){
    half8 a8=pd[i], c8=ps[i];
    #pragma unroll
    for(int k=0;k<8;k++){
      int j = 8*i+k;
      float t = gelu_f(((float)a8[k]-(float)c8[k]) + cvec[j]);
      o0 += t*W2[j*3+0]; o1 += t*W2[j*3+1]; o2 += t*W2[j*3+2];
    }
  }
  __builtin_nontemporal_store(o0, out + (size_t)e*3+0);
  __builtin_nontemporal_store(o1, out + (size_t)e*3+1);
  __builtin_nontemporal_store(o2, out + (size_t)e*3+2);
}

extern "C" void kernel_launch(void* const* d_in, const int* in_sizes, int n_in,
                              void* d_out, int out_size, void* d_ws, size_t ws_size,
                              hipStream_t stream)
{
  (void)in_sizes; (void)n_in; (void)out_size; (void)ws_size;
  const float* x     = (const float*)d_in[0];
  const int*   ei    = (const int*)d_in[1];
  const float* eW1   = (const float*)d_in[2];
  const float* eb1   = (const float*)d_in[3];
  const float* ebn1g = (const float*)d_in[4];
  const float* ebn1b = (const float*)d_in[5];
  const float* eW2   = (const float*)d_in[6];
  const float* eb2   = (const float*)d_in[7];
  const float* ebn2g = (const float*)d_in[8];
  const float* ebn2b = (const float*)d_in[9];
  const float* msgW  = (const float*)d_in[10];
  const float* msgb  = (const float*)d_in[11];
  const float* msglng= (const float*)d_in[12];
  const float* msglnb= (const float*)d_in[13];
  const float* updW  = (const float*)d_in[14];
  const float* updb  = (const float*)d_in[15];
  const float* updlng= (const float*)d_in[16];
  const float* updlnb= (const float*)d_in[17];
  const float* fW1   = (const float*)d_in[18];
  const float* fb1   = (const float*)d_in[19];
  const float* fbng  = (const float*)d_in[20];
  const float* fbnb  = (const float*)d_in[21];
  const float* fW2   = (const float*)d_in[22];
  const float* fb2   = (const float*)d_in[23];
  float* out = (float*)d_out;

  // workspace: h, pre, P, R, agg (each NN*32 f32), Qh (NN*32 f16), ints
  float* f   = (float*)d_ws;
  float* h   = f;
  float* pre = f + 1*(size_t)NN*32;
  float* P   = f + 2*(size_t)NN*32;
  float* R   = f + 3*(size_t)NN*32;
  float* agg = f + 4*(size_t)NN*32;
  _Float16* Qh = (_Float16*)(f + 5*(size_t)NN*32);   // NN*32 halves
  _Float16* y1 = (_Float16*)P;                        // NN*32 halves (aliases P, dead then)
  _Float16* y2 = y1 + (size_t)NN*32;                  // NN*32 halves (still within P)
  int* ip      = (int*)(f + 5*(size_t)NN*32 + (size_t)NN*16);
  int* row_ptr = ip;            // NN+1
  int* cnt     = ip + NN + 1;   // NN (dead after fill -> reused for cvec)
  int* csr     = ip + 2*NN + 1; // NE
  float* cvec  = (float*)cnt;   // 64 floats, written by embed_pqr (after fill)

  hipMemsetAsync(cnt, 0, NN*sizeof(int), stream);
  hist_kernel<<<(NE/4+255)/256, 256, 0, stream>>>(ei, cnt);
  scan_kernel<<<1, 1024, 0, stream>>>(cnt, row_ptr);
  hipMemsetAsync(cnt, 0, NN*sizeof(int), stream);
  fill_kernel<<<(NE/4+255)/256, 256, 0, stream>>>(ei, row_ptr, cnt, csr);

  embed_pqr_kernel<<<(NN+255)/256, 256, 0, stream>>>(x, eW1, eb1, ebn1g, ebn1b,
      eW2, eb2, ebn2g, ebn2b,
      msgW, msgb, updW, updb,
      fb1, fbng, fbnb,
      h, pre, P, Qh, R, cvec);

  for(int l=0; l<3; l++){
    msg_kernel<<<((NN*16)+255)/256, 256, 0, stream>>>(P, Qh, row_ptr, csr,
        msglng + l*32, msglnb + l*32, agg);
    if(l < 2){
      upd_pqr_kernel<<<(NN+255)/256, 256, 0, stream>>>(agg, R,
          updW + l*2048 + 1024, updlng + l*32, updlnb + l*32,
          msgW + (l+1)*2048, msgb + (l+1)*32,
          updW + (l+1)*2048, updb + (l+1)*32,
          h, P, Qh, R);
    } else {
      upd_fin_kernel<<<(NN+255)/256, 256, 0, stream>>>(agg, R,
          updW + l*2048 + 1024, updlng + l*32, updlnb + l*32,
          h, pre, fW1, fbng, y1, y2);
    }
  }

  finalA_kernel<<<(NE+255)/256, 256, 0, stream>>>(y1, ei, cvec,      fW2,      fb2, out);
  finalB_kernel<<<(NE+255)/256, 256, 0, stream>>>(y2, ei, cvec + 32, fW2 + 96, out);
}

// Round 5
// 544.783 us; speedup vs baseline: 2.6841x; 1.2262x over previous
//
#include <hip/hip_runtime.h>

#define NN 50000
#define NE 1600000
constexpr float LN_EPS = 1e-5f;

typedef _Float16 half8 __attribute__((ext_vector_type(8)));

// Branchless erf-GELU: Abramowitz-Stegun 7.1.26, |eps| <= 1.5e-7
__device__ __forceinline__ float gelu_f(float x){
  float ax = fabsf(x) * 0.70710678118654752440f;
  float t  = __builtin_amdgcn_rcpf(fmaf(0.3275911f, ax, 1.0f));
  float e  = __expf(-ax*ax);
  float p  = t*fmaf(t, fmaf(t, fmaf(t, fmaf(t, 1.061405429f, -1.453152027f),
                                    1.421413741f), -0.284496736f), 0.254829592f);
  float er = fmaf(-p, e, 1.0f);
  return 0.5f * x * (1.0f + copysignf(er, x));
}

// ---------------- CSR build ----------------
// hist: count degrees AND capture each edge's within-node rank (atomic return)
__global__ __launch_bounds__(256) void hist_kernel(const int* __restrict__ ei,
    int* __restrict__ cnt, int* __restrict__ rank){
  int t = blockIdx.x*256 + threadIdx.x;
  if(t < NE/4){
    int4 d = ((const int4*)(ei + NE))[t];
    int4 r;
    r.x = atomicAdd(&cnt[d.x],1);
    r.y = atomicAdd(&cnt[d.y],1);
    r.z = atomicAdd(&cnt[d.z],1);
    r.w = atomicAdd(&cnt[d.w],1);
    ((int4*)rank)[t] = r;
  }
}

#define CHUNK 52  // 1024*52 = 53248 >= 50000
__global__ __launch_bounds__(1024) void scan_kernel(const int* __restrict__ deg, int* __restrict__ row_ptr){
  __shared__ int sums[1024];
  int t = threadIdx.x;
  int base = t*CHUNK;
  int4 v[13];
  int ssum = 0;
  #pragma unroll
  for(int i=0;i<13;i++){
    int idx = base + 4*i;
    if(idx + 3 < NN){
      v[i] = ((const int4*)deg)[(base>>2)+i];
    } else {
      v[i].x = (idx+0<NN)?deg[idx+0]:0; v[i].y = (idx+1<NN)?deg[idx+1]:0;
      v[i].z = (idx+2<NN)?deg[idx+2]:0; v[i].w = (idx+3<NN)?deg[idx+3]:0;
    }
    ssum += v[i].x + v[i].y + v[i].z + v[i].w;
  }
  sums[t]=ssum;
  __syncthreads();
  for(int off=1; off<1024; off<<=1){
    int vv = (t>=off) ? sums[t-off] : 0;
    __syncthreads();
    sums[t] += vv;
    __syncthreads();
  }
  int run = (t>0) ? sums[t-1] : 0;
  #pragma unroll
  for(int i=0;i<13;i++){
    int idx = base + 4*i;
    int4 o;
    o.x = run; run += v[i].x;
    o.y = run; run += v[i].y;
    o.z = run; run += v[i].z;
    o.w = run; run += v[i].w;
    if(idx + 3 < NN){
      ((int4*)row_ptr)[(base>>2)+i] = o;
    } else {
      if(idx+0<NN) row_ptr[idx+0]=o.x;
      if(idx+1<NN) row_ptr[idx+1]=o.y;
      if(idx+2<NN) row_ptr[idx+2]=o.z;
      if(idx+3<NN) row_ptr[idx+3]=o.w;
    }
  }
  if(t==1023) row_ptr[NN] = sums[1023];
}

// fill: no atomics — position = row_ptr[d] + rank[e]; pure scatter-store
__global__ __launch_bounds__(256) void fill_kernel(const int* __restrict__ ei,
    const int* __restrict__ row_ptr, const int* __restrict__ rank, int* __restrict__ csr_src){
  int t = blockIdx.x*256 + threadIdx.x;
  if(t < NE/4){
    int4 d  = ((const int4*)(ei + NE))[t];
    int4 sv = ((const int4*)ei)[t];
    int4 rk = ((const int4*)rank)[t];
    csr_src[row_ptr[d.x] + rk.x] = sv.x;
    csr_src[row_ptr[d.y] + rk.y] = sv.y;
    csr_src[row_ptr[d.z] + rk.z] = sv.z;
    csr_src[row_ptr[d.w] + rk.w] = sv.w;
  }
}

// ---------------- embed MLP + layer-0 PQR (fused) + cvec ----------------
__global__ __launch_bounds__(256) void embed_pqr_kernel(
    const float* __restrict__ x,
    const float* __restrict__ W1, const float* __restrict__ b1,
    const float* __restrict__ g1, const float* __restrict__ bb1,
    const float* __restrict__ W2, const float* __restrict__ b2,
    const float* __restrict__ g2, const float* __restrict__ bb2,
    const float* __restrict__ Wm, const float* __restrict__ bm,
    const float* __restrict__ Wu, const float* __restrict__ bu,
    const float* __restrict__ fb1, const float* __restrict__ fbng, const float* __restrict__ fbnb,
    float* __restrict__ h, float* __restrict__ pre,
    float* __restrict__ P, _Float16* __restrict__ Qh, float* __restrict__ R,
    float* __restrict__ cvec)
{
  int n = blockIdx.x*256 + threadIdx.x;
  const float rs = rsqrtf(1.0f + LN_EPS);
  if(n < 64) cvec[n] = fmaf(fb1[n], fbng[n]*rs, fbnb[n]);
  if(n >= NN) return;
  float xv[16];
  const float4* xp = (const float4*)(x + (size_t)n*16);
  #pragma unroll
  for(int i=0;i<4;i++){ float4 t=xp[i]; xv[4*i]=t.x; xv[4*i+1]=t.y; xv[4*i+2]=t.z; xv[4*i+3]=t.w; }
  float a1[64];
  #pragma unroll
  for(int j=0;j<64;j++) a1[j]=b1[j];
  #pragma unroll
  for(int k=0;k<16;k++){
    float xk=xv[k];
    #pragma unroll
    for(int j=0;j<64;j++) a1[j] += xk * W1[k*64+j];
  }
  #pragma unroll
  for(int j=0;j<64;j++) a1[j] = gelu_f(a1[j]*(g1[j]*rs) + bb1[j]);
  float hv[32];
  #pragma unroll
  for(int j=0;j<32;j++) hv[j]=b2[j];
  #pragma unroll
  for(int k=0;k<64;k++){
    float tk=a1[k];
    #pragma unroll
    for(int j=0;j<32;j++) hv[j] += tk * W2[k*32+j];
  }
  #pragma unroll
  for(int j=0;j<32;j++){
    hv[j] = gelu_f(hv[j]*(g2[j]*rs) + bb2[j]);
    h[(size_t)n*32+j]=hv[j]; pre[(size_t)n*32+j]=hv[j];
  }
  float ap[32], aq[32], ar[32];
  #pragma unroll
  for(int j=0;j<32;j++){ ap[j]=bm[j]; aq[j]=0.f; ar[j]=bu[j]; }
  #pragma unroll
  for(int k=0;k<32;k++){
    float hk = hv[k];
    #pragma unroll
    for(int j=0;j<32;j++){
      ap[j] += hk * Wm[k*32+j];
      aq[j] += hk * Wm[(32+k)*32+j];
      ar[j] += hk * Wu[k*32+j];
    }
  }
  #pragma unroll
  for(int j=0;j<32;j++){ P[(size_t)n*32+j]=ap[j]; R[(size_t)n*32+j]=ar[j]; }
  half8* qo = (half8*)(Qh + (size_t)n*32);
  #pragma unroll
  for(int i=0;i<4;i++){
    half8 q;
    #pragma unroll
    for(int k=0;k<8;k++) q[k] = (_Float16)aq[8*i+k];
    qo[i] = q;
  }
}

// -------- message+aggregate: 4 lanes per edge (slot,q), one 64B line per edge --------
__global__ __launch_bounds__(256) void msg_kernel(
    const float* __restrict__ P, const _Float16* __restrict__ Qh,
    const int* __restrict__ row_ptr, const int* __restrict__ csr_src,
    const float* __restrict__ mg, const float* __restrict__ mb,
    float* __restrict__ aggO)
{
  int tid = blockIdx.x*256 + threadIdx.x;   // grid = NN*16 exactly
  int n = tid >> 4;
  int s = tid & 15;
  int slot = s >> 2;   // edge slot 0..3
  int q = s & 3;       // feature quarter 0..3
  float4 mg0 = *(const float4*)(mg + q*8);
  float4 mg1 = *(const float4*)(mg + q*8 + 4);
  float4 mb0 = *(const float4*)(mb + q*8);
  float4 mb1 = *(const float4*)(mb + q*8 + 4);
  float mgq[8] = {mg0.x,mg0.y,mg0.z,mg0.w,mg1.x,mg1.y,mg1.z,mg1.w};
  float mbq[8] = {mb0.x,mb0.y,mb0.z,mb0.w,mb1.x,mb1.y,mb1.z,mb1.w};
  float4 pl0 = *(const float4*)(P + (size_t)n*32 + q*8);
  float4 pl1 = *(const float4*)(P + (size_t)n*32 + q*8 + 4);
  float p8[8] = {pl0.x,pl0.y,pl0.z,pl0.w,pl1.x,pl1.y,pl1.z,pl1.w};
  float agg8[8] = {0,0,0,0,0,0,0,0};
  int e0 = row_ptr[n], e1 = row_ptr[n+1];
  int e = e0 + slot;
  int src = (e < e1) ? csr_src[e] : 0;
  half8 qv = *(const half8*)(Qh + (size_t)src*32 + q*8);
  while(e < e1){
    int e2 = e + 4;
    int src2 = (e2 < e1) ? csr_src[e2] : 0;
    half8 qv2 = *(const half8*)(Qh + (size_t)src2*32 + q*8);   // prefetch next
    float v[8];
    #pragma unroll
    for(int k=0;k<8;k++) v[k] = p8[k] + (float)qv[k];
    float ps = ((v[0]+v[1])+(v[2]+v[3])) + ((v[4]+v[5])+(v[6]+v[7]));
    ps += __shfl_xor(ps,1); ps += __shfl_xor(ps,2);
    float mean = ps * 0.03125f;
    float vs = 0.f;
    #pragma unroll
    for(int k=0;k<8;k++){ float dd = v[k]-mean; vs += dd*dd; v[k]=dd; }
    vs += __shfl_xor(vs,1); vs += __shfl_xor(vs,2);
    float rstd = rsqrtf(vs*0.03125f + LN_EPS);
    #pragma unroll
    for(int k=0;k<8;k++) agg8[k] += gelu_f(v[k]*rstd*mgq[k] + mbq[k]);
    qv = qv2; e = e2;
  }
  // combine the 4 edge slots (same q, different slot)
  #pragma unroll
  for(int k=0;k<8;k++) agg8[k] += __shfl_xor(agg8[k], 4);
  #pragma unroll
  for(int k=0;k<8;k++) agg8[k] += __shfl_xor(agg8[k], 8);
  if(slot==0){
    float4 s0; s0.x=agg8[0]; s0.y=agg8[1]; s0.z=agg8[2]; s0.w=agg8[3];
    float4 s1; s1.x=agg8[4]; s1.y=agg8[5]; s1.z=agg8[6]; s1.w=agg8[7];
    *(float4*)(aggO + (size_t)n*32 + q*8)     = s0;
    *(float4*)(aggO + (size_t)n*32 + q*8 + 4) = s1;
  }
}

// -------- update MLP + next-layer PQR (fused, node per lane) --------
__global__ __launch_bounds__(256) void upd_pqr_kernel(
    const float* __restrict__ aggI, const float* __restrict__ Rio,
    const float* __restrict__ Ub,
    const float* __restrict__ ug, const float* __restrict__ ub,
    const float* __restrict__ Wm2, const float* __restrict__ bm2,
    const float* __restrict__ Wu2, const float* __restrict__ bu2,
    float* __restrict__ h,
    float* __restrict__ P, _Float16* __restrict__ Qh, float* __restrict__ Rout)
{
  int n = blockIdx.x*256 + threadIdx.x;
  if(n >= NN) return;
  float agg[32], u[32];
  const float4* ap4 = (const float4*)(aggI + (size_t)n*32);
  const float4* rp4 = (const float4*)(Rio + (size_t)n*32);
  #pragma unroll
  for(int i=0;i<8;i++){ float4 t=ap4[i]; agg[4*i]=t.x; agg[4*i+1]=t.y; agg[4*i+2]=t.z; agg[4*i+3]=t.w; }
  #pragma unroll
  for(int i=0;i<8;i++){ float4 t=rp4[i]; u[4*i]=t.x; u[4*i+1]=t.y; u[4*i+2]=t.z; u[4*i+3]=t.w; }
  #pragma unroll
  for(int k=0;k<32;k++){
    float a = agg[k];
    #pragma unroll
    for(int j=0;j<32;j++) u[j] += a * Ub[k*32+j];
  }
  float s0=0,s1=0,s2=0,s3=0;
  #pragma unroll
  for(int i=0;i<8;i++){ s0+=u[4*i]; s1+=u[4*i+1]; s2+=u[4*i+2]; s3+=u[4*i+3]; }
  float mean = ((s0+s1)+(s2+s3)) * 0.03125f;
  s0=s1=s2=s3=0.f;
  #pragma unroll
  for(int i=0;i<8;i++){
    float d0=u[4*i]-mean, d1=u[4*i+1]-mean, d2=u[4*i+2]-mean, d3=u[4*i+3]-mean;
    s0+=d0*d0; s1+=d1*d1; s2+=d2*d2; s3+=d3*d3;
    u[4*i]=d0; u[4*i+1]=d1; u[4*i+2]=d2; u[4*i+3]=d3;
  }
  float rstd = rsqrtf(((s0+s1)+(s2+s3))*0.03125f + LN_EPS);
  float hv[32];
  const float4* hp4 = (const float4*)(h + (size_t)n*32);
  #pragma unroll
  for(int i=0;i<8;i++){ float4 t=hp4[i]; hv[4*i]=t.x; hv[4*i+1]=t.y; hv[4*i+2]=t.z; hv[4*i+3]=t.w; }
  #pragma unroll
  for(int j=0;j<32;j++) hv[j] += gelu_f(u[j]*rstd*ug[j] + ub[j]);
  float4* ho = (float4*)(h + (size_t)n*32);
  #pragma unroll
  for(int i=0;i<8;i++){ float4 t; t.x=hv[4*i]; t.y=hv[4*i+1]; t.z=hv[4*i+2]; t.w=hv[4*i+3]; ho[i]=t; }
  float pq[32], qq[32], rr[32];
  #pragma unroll
  for(int j=0;j<32;j++){ pq[j]=bm2[j]; qq[j]=0.f; rr[j]=bu2[j]; }
  #pragma unroll
  for(int k=0;k<32;k++){
    float hk = hv[k];
    #pragma unroll
    for(int j=0;j<32;j++){
      pq[j] += hk * Wm2[k*32+j];
      qq[j] += hk * Wm2[(32+k)*32+j];
      rr[j] += hk * Wu2[k*32+j];
    }
  }
  #pragma unroll
  for(int j=0;j<32;j++){ P[(size_t)n*32+j]=pq[j]; Rout[(size_t)n*32+j]=rr[j]; }
  half8* qo = (half8*)(Qh + (size_t)n*32);
  #pragma unroll
  for(int i=0;i<4;i++){
    half8 q;
    #pragma unroll
    for(int k=0;k<8;k++) q[k] = (_Float16)qq[8*i+k];
    qo[i] = q;
  }
}

// -------- last-layer update + final node matmul, split-half fp16 outputs --------
__global__ __launch_bounds__(256) void upd_fin_kernel(
    const float* __restrict__ aggI, const float* __restrict__ Rio,
    const float* __restrict__ Ub,
    const float* __restrict__ ug, const float* __restrict__ ub,
    const float* __restrict__ h, const float* __restrict__ pre,
    const float* __restrict__ fW1, const float* __restrict__ fbng,
    _Float16* __restrict__ y1, _Float16* __restrict__ y2)
{
  int n = blockIdx.x*256 + threadIdx.x;
  if(n >= NN) return;
  const float rs = rsqrtf(1.0f + LN_EPS);
  float agg[32], u[32];
  const float4* ap4 = (const float4*)(aggI + (size_t)n*32);
  const float4* rp4 = (const float4*)(Rio + (size_t)n*32);
  #pragma unroll
  for(int i=0;i<8;i++){ float4 t=ap4[i]; agg[4*i]=t.x; agg[4*i+1]=t.y; agg[4*i+2]=t.z; agg[4*i+3]=t.w; }
  #pragma unroll
  for(int i=0;i<8;i++){ float4 t=rp4[i]; u[4*i]=t.x; u[4*i+1]=t.y; u[4*i+2]=t.z; u[4*i+3]=t.w; }
  #pragma unroll
  for(int k=0;k<32;k++){
    float a = agg[k];
    #pragma unroll
    for(int j=0;j<32;j++) u[j] += a * Ub[k*32+j];
  }
  float s0=0,s1=0,s2=0,s3=0;
  #pragma unroll
  for(int i=0;i<8;i++){ s0+=u[4*i]; s1+=u[4*i+1]; s2+=u[4*i+2]; s3+=u[4*i+3]; }
  float mean = ((s0+s1)+(s2+s3)) * 0.03125f;
  s0=s1=s2=s3=0.f;
  #pragma unroll
  for(int i=0;i<8;i++){
    float d0=u[4*i]-mean, d1=u[4*i+1]-mean, d2=u[4*i+2]-mean, d3=u[4*i+3]-mean;
    s0+=d0*d0; s1+=d1*d1; s2+=d2*d2; s3+=d3*d3;
    u[4*i]=d0; u[4*i+1]=d1; u[4*i+2]=d2; u[4*i+3]=d3;
  }
  float rstd = rsqrtf(((s0+s1)+(s2+s3))*0.03125f + LN_EPS);
  float hv[32];
  const float4* hp4 = (const float4*)(h + (size_t)n*32);
  const float4* pp4 = (const float4*)(pre + (size_t)n*32);
  #pragma unroll
  for(int i=0;i<8;i++){ float4 t=hp4[i]; hv[4*i]=t.x; hv[4*i+1]=t.y; hv[4*i+2]=t.z; hv[4*i+3]=t.w; }
  #pragma unroll
  for(int j=0;j<32;j++) hv[j] += gelu_f(u[j]*rstd*ug[j] + ub[j]);
  #pragma unroll
  for(int i=0;i<8;i++){ float4 t=pp4[i]; hv[4*i]+=t.x; hv[4*i+1]+=t.y; hv[4*i+2]+=t.z; hv[4*i+3]+=t.w; }
  float acc[64];
  #pragma unroll
  for(int j=0;j<64;j++) acc[j]=0.f;
  #pragma unroll
  for(int k=0;k<32;k++){
    float hk = hv[k];
    #pragma unroll
    for(int j=0;j<64;j++) acc[j] += hk * fW1[k*64+j];
  }
  half8* yo1 = (half8*)(y1 + (size_t)n*32);
  half8* yo2 = (half8*)(y2 + (size_t)n*32);
  #pragma unroll
  for(int i=0;i<4;i++){
    half8 qa, qb;
    #pragma unroll
    for(int k=0;k<8;k++){
      qa[k] = (_Float16)(acc[8*i+k]    * (fbng[8*i+k]*rs));
      qb[k] = (_Float16)(acc[32+8*i+k] * (fbng[32+8*i+k]*rs));
    }
    yo1[i] = qa; yo2[i] = qb;
  }
}

// ---------------- final per-edge: 4 lanes per edge, feature-split passes ----------------
__global__ __launch_bounds__(256) void finalA_kernel(
    const _Float16* __restrict__ y, const int* __restrict__ ei,
    const float* __restrict__ cvec, const float* __restrict__ W2,
    const float* __restrict__ b2, float* __restrict__ out)
{
  int t = blockIdx.x*256 + threadIdx.x;   // grid = NE*4 exactly
  int e = t >> 2, q = t & 3;
  int s = __builtin_nontemporal_load(ei + e);
  int d = __builtin_nontemporal_load(ei + NE + e);
  half8 a8 = *(const half8*)(y + (size_t)d*32 + q*8);
  half8 c8 = *(const half8*)(y + (size_t)s*32 + q*8);
  float4 cv0 = *(const float4*)(cvec + q*8);
  float4 cv1 = *(const float4*)(cvec + q*8 + 4);
  float cq[8] = {cv0.x,cv0.y,cv0.z,cv0.w,cv1.x,cv1.y,cv1.z,cv1.w};
  const float4* wp = (const float4*)(W2 + q*24);
  float4 w0=wp[0], w1=wp[1], w2=wp[2], w3=wp[3], w4=wp[4], w5=wp[5];
  float w[24] = {w0.x,w0.y,w0.z,w0.w, w1.x,w1.y,w1.z,w1.w, w2.x,w2.y,w2.z,w2.w,
                 w3.x,w3.y,w3.z,w3.w, w4.x,w4.y,w4.z,w4.w, w5.x,w5.y,w5.z,w5.w};
  float o0=0.f,o1=0.f,o2=0.f;
  #pragma unroll
  for(int k=0;k<8;k++){
    float tt = gelu_f(((float)a8[k]-(float)c8[k]) + cq[k]);
    o0 += tt*w[3*k]; o1 += tt*w[3*k+1]; o2 += tt*w[3*k+2];
  }
  o0 += __shfl_xor(o0,1); o0 += __shfl_xor(o0,2);
  o1 += __shfl_xor(o1,1); o1 += __shfl_xor(o1,2);
  o2 += __shfl_xor(o2,1); o2 += __shfl_xor(o2,2);
  float ov = (q==0) ? o0 + b2[0] : (q==1) ? o1 + b2[1] : o2 + b2[2];
  if(q < 3) __builtin_nontemporal_store(ov, out + (size_t)e*3 + q);
}

__global__ __launch_bounds__(256) void finalB_kernel(
    const _Float16* __restrict__ y, const int* __restrict__ ei,
    const float* __restrict__ cvec,   // cvec+32
    const float* __restrict__ W2,     // W2+96
    float* __restrict__ out)
{
  int t = blockIdx.x*256 + threadIdx.x;
  int e = t >> 2, q = t & 3;
  float prev = 0.f;
  if(q < 3) prev = __builtin_nontemporal_load(out + (size_t)e*3 + q);
  int s = __builtin_nontemporal_load(ei + e);
  int d = __builtin_nontemporal_load(ei + NE + e);
  half8 a8 = *(const half8*)(y + (size_t)d*32 + q*8);
  half8 c8 = *(const half8*)(y + (size_t)s*32 + q*8);
  float4 cv0 = *(const float4*)(cvec + q*8);
  float4 cv1 = *(const float4*)(cvec + q*8 + 4);
  float cq[8] = {cv0.x,cv0.y,cv0.z,cv0.w,cv1.x,cv1.y,cv1.z,cv1.w};
  const float4* wp = (const float4*)(W2 + q*24);
  float4 w0=wp[0], w1=wp[1], w2=wp[2], w3=wp[3], w4=wp[4], w5=wp[5];
  float w[24] = {w0.x,w0.y,w0.z,w0.w, w1.x,w1.y,w1.z,w1.w, w2.x,w2.y,w2.z,w2.w,
                 w3.x,w3.y,w3.z,w3.w, w4.x,w4.y,w4.z,w4.w, w5.x,w5.y,w5.z,w5.w};
  float o0=0.f,o1=0.f,o2=0.f;
  #pragma unroll
  for(int k=0;k<8;k++){
    float tt = gelu_f(((float)a8[k]-(float)c8[k]) + cq[k]);
    o0 += tt*w[3*k]; o1 += tt*w[3*k+1]; o2 += tt*w[3*k+2];
  }
  o0 += __shfl_xor(o0,1); o0 += __shfl_xor(o0,2);
  o1 += __shfl_xor(o1,1); o1 += __shfl_xor(o1,2);
  o2 += __shfl_xor(o2,1); o2 += __shfl_xor(o2,2);
  float ov = prev + ((q==0) ? o0 : (q==1) ? o1 : o2);
  if(q < 3) __builtin_nontemporal_store(ov, out + (size_t)e*3 + q);
}

extern "C" void kernel_launch(void* const* d_in, const int* in_sizes, int n_in,
                              void* d_out, int out_size, void* d_ws, size_t ws_size,
                              hipStream_t stream)
{
  (void)in_sizes; (void)n_in; (void)out_size; (void)ws_size;
  const float* x     = (const float*)d_in[0];
  const int*   ei    = (const int*)d_in[1];
  const float* eW1   = (const float*)d_in[2];
  const float* eb1   = (const float*)d_in[3];
  const float* ebn1g = (const float*)d_in[4];
  const float* ebn1b = (const float*)d_in[5];
  const float* eW2   = (const float*)d_in[6];
  const float* eb2   = (const float*)d_in[7];
  const float* ebn2g = (const float*)d_in[8];
  const float* ebn2b = (const float*)d_in[9];
  const float* msgW  = (const float*)d_in[10];
  const float* msgb  = (const float*)d_in[11];
  const float* msglng= (const float*)d_in[12];
  const float* msglnb= (const float*)d_in[13];
  const float* updW  = (const float*)d_in[14];
  const float* updb  = (const float*)d_in[15];
  const float* updlng= (const float*)d_in[16];
  const float* updlnb= (const float*)d_in[17];
  const float* fW1   = (const float*)d_in[18];
  const float* fb1   = (const float*)d_in[19];
  const float* fbng  = (const float*)d_in[20];
  const float* fbnb  = (const float*)d_in[21];
  const float* fW2   = (const float*)d_in[22];
  const float* fb2   = (const float*)d_in[23];
  float* out = (float*)d_out;

  float* f   = (float*)d_ws;
  float* h   = f;
  float* pre = f + 1*(size_t)NN*32;
  float* P   = f + 2*(size_t)NN*32;
  float* R   = f + 3*(size_t)NN*32;
  float* agg = f + 4*(size_t)NN*32;
  _Float16* Qh = (_Float16*)(f + 5*(size_t)NN*32);   // NN*32 halves
  _Float16* y1 = (_Float16*)P;                        // NN*32 halves
  _Float16* y2 = y1 + (size_t)NN*32;                  // NN*32 halves
  int* ip      = (int*)(f + 5*(size_t)NN*32 + (size_t)NN*16);
  int* cnt     = ip;              // NN (dead after scan -> reused for cvec)
  int* row_ptr = ip + NN;         // NN+1 (16B-aligned: NN*4 bytes % 16 == 0)
  int* csr     = ip + 2*NN + 4;   // NE
  int* rank    = (int*)agg;       // NE ints, aliases agg (free until msg)
  float* cvec  = (float*)cnt;     // 64 floats, written by embed_pqr (after scan)

  hipMemsetAsync(cnt, 0, NN*sizeof(int), stream);
  hist_kernel<<<(NE/4+255)/256, 256, 0, stream>>>(ei, cnt, rank);
  scan_kernel<<<1, 1024, 0, stream>>>(cnt, row_ptr);
  fill_kernel<<<(NE/4+255)/256, 256, 0, stream>>>(ei, row_ptr, rank, csr);

  embed_pqr_kernel<<<(NN+255)/256, 256, 0, stream>>>(x, eW1, eb1, ebn1g, ebn1b,
      eW2, eb2, ebn2g, ebn2b,
      msgW, msgb, updW, updb,
      fb1, fbng, fbnb,
      h, pre, P, Qh, R, cvec);

  for(int l=0; l<3; l++){
    msg_kernel<<<(NN*16)/256, 256, 0, stream>>>(P, Qh, row_ptr, csr,
        msglng + l*32, msglnb + l*32, agg);
    if(l < 2){
      upd_pqr_kernel<<<(NN+255)/256, 256, 0, stream>>>(agg, R,
          updW + l*2048 + 1024, updlng + l*32, updlnb + l*32,
          msgW + (l+1)*2048, msgb + (l+1)*32,
          updW + (l+1)*2048, updb + (l+1)*32,
          h, P, Qh, R);
    } else {
      upd_fin_kernel<<<(NN+255)/256, 256, 0, stream>>>(agg, R,
          updW + l*2048 + 1024, updlng + l*32, updlnb + l*32,
          h, pre, fW1, fbng, y1, y2);
    }
  }

  finalA_kernel<<<(NE*4)/256, 256, 0, stream>>>(y1, ei, cvec,      fW2,      fb2, out);
  finalB_kernel<<<(NE*4)/256, 256, 0, stream>>>(y2, ei, cvec + 32, fW2 + 96, out);
}

// Round 6
// 517.070 us; speedup vs baseline: 2.8280x; 1.0536x over previous
//
#include <hip/hip_runtime.h>

#define NN 50000
#define NE 1600000
#define HIST_B 1563   // ceil((NE/4)/256)
#define EMB_B  782    // ceil((NN*4)/256)
constexpr float LN_EPS = 1e-5f;

typedef _Float16 half8 __attribute__((ext_vector_type(8)));

__device__ __forceinline__ float gelu_f(float x){
  float ax = fabsf(x) * 0.70710678118654752440f;
  float t  = __builtin_amdgcn_rcpf(fmaf(0.3275911f, ax, 1.0f));
  float e  = __expf(-ax*ax);
  float p  = t*fmaf(t, fmaf(t, fmaf(t, fmaf(t, 1.061405429f, -1.453152027f),
                                    1.421413741f), -0.284496736f), 0.254829592f);
  float er = fmaf(-p, e, 1.0f);
  return 0.5f * x * (1.0f + copysignf(er, x));
}

__device__ __forceinline__ void ld8(const float* __restrict__ p, float* r){
  float4 a=((const float4*)p)[0], b=((const float4*)p)[1];
  r[0]=a.x;r[1]=a.y;r[2]=a.z;r[3]=a.w;r[4]=b.x;r[5]=b.y;r[6]=b.z;r[7]=b.w;
}
__device__ __forceinline__ void ld16(const float* __restrict__ p, float* r){ ld8(p,r); ld8(p+8,r+8); }
__device__ __forceinline__ void st8(float* __restrict__ p, const float* r){
  float4 a,b; a.x=r[0];a.y=r[1];a.z=r[2];a.w=r[3]; b.x=r[4];b.y=r[5];b.z=r[6];b.w=r[7];
  ((float4*)p)[0]=a; ((float4*)p)[1]=b;
}

// ---------------- fused: hist (blocks 0..HIST_B) || embed+PQR0 (4 lanes/node) ----------------
__global__ __launch_bounds__(256) void hist_embed_kernel(
    const int* __restrict__ ei, int* __restrict__ cnt, int* __restrict__ rank,
    const float* __restrict__ x,
    const float* __restrict__ W1, const float* __restrict__ b1,
    const float* __restrict__ g1, const float* __restrict__ bb1,
    const float* __restrict__ W2, const float* __restrict__ b2,
    const float* __restrict__ g2, const float* __restrict__ bb2,
    const float* __restrict__ Wm, const float* __restrict__ bm,
    const float* __restrict__ Wu, const float* __restrict__ bu,
    const float* __restrict__ fb1, const float* __restrict__ fbng, const float* __restrict__ fbnb,
    float* __restrict__ h, float* __restrict__ pre,
    float* __restrict__ P, _Float16* __restrict__ Qh, float* __restrict__ R,
    float* __restrict__ cvec)
{
  if(blockIdx.x < HIST_B){
    int t = blockIdx.x*256 + threadIdx.x;
    if(t < NE/4){
      int4 d = ((const int4*)(ei + NE))[t];
      int4 r;
      r.x = atomicAdd(&cnt[d.x],1);
      r.y = atomicAdd(&cnt[d.y],1);
      r.z = atomicAdd(&cnt[d.z],1);
      r.w = atomicAdd(&cnt[d.w],1);
      ((int4*)rank)[t] = r;
    }
    return;
  }
  int t = (blockIdx.x - HIST_B)*256 + threadIdx.x;
  const float rs = rsqrtf(1.0f + LN_EPS);
  if(t < 64) cvec[t] = fmaf(fb1[t], fbng[t]*rs, fbnb[t]);
  int n = t >> 2, q = t & 3;
  if(n >= NN) return;
  int base = threadIdx.x & 60;
  // x row: 4 lanes cover one 64B line
  float4 xq = ((const float4*)x)[n*4 + q];
  float xv[16];
  #pragma unroll
  for(int m=0;m<4;m++){
    xv[4*m+0]=__shfl(xq.x, base|m);
    xv[4*m+1]=__shfl(xq.y, base|m);
    xv[4*m+2]=__shfl(xq.z, base|m);
    xv[4*m+3]=__shfl(xq.w, base|m);
  }
  // a1 slice [16q,16q+16)
  float a1q[16]; ld16(b1 + q*16, a1q);
  #pragma unroll
  for(int k=0;k<16;k++){
    float w[16]; ld16(W1 + k*64 + q*16, w);
    float xk = xv[k];
    #pragma unroll
    for(int j=0;j<16;j++) a1q[j] += xk * w[j];
  }
  { float g[16], b[16]; ld16(g1+q*16,g); ld16(bb1+q*16,b);
    #pragma unroll
    for(int j=0;j<16;j++) a1q[j] = gelu_f(a1q[j]*(g[j]*rs) + b[j]); }
  // hv slice [8q,8q+8)
  float hq[8]; ld8(b2 + q*8, hq);
  #pragma unroll
  for(int m=0;m<4;m++){
    #pragma unroll
    for(int kk=0;kk<16;kk++){
      float a = __shfl(a1q[kk], base|m);
      float w[8]; ld8(W2 + (m*16+kk)*32 + q*8, w);
      #pragma unroll
      for(int j=0;j<8;j++) hq[j] += a * w[j];
    }
  }
  { float g[8], b[8]; ld8(g2+q*8,g); ld8(bb2+q*8,b);
    #pragma unroll
    for(int j=0;j<8;j++) hq[j] = gelu_f(hq[j]*(g[j]*rs) + b[j]); }
  st8(h   + (size_t)n*32 + q*8, hq);
  st8(pre + (size_t)n*32 + q*8, hq);
  // PQR layer 0, slices [8q,8q+8)
  float apv[8], aqv[8], arv[8];
  ld8(bm+q*8, apv); ld8(bu+q*8, arv);
  #pragma unroll
  for(int j=0;j<8;j++) aqv[j]=0.f;
  #pragma unroll
  for(int m=0;m<4;m++){
    #pragma unroll
    for(int kk=0;kk<8;kk++){
      float hk = __shfl(hq[kk], base|m);
      int k = m*8+kk;
      float wm[8],wq[8],wu[8];
      ld8(Wm + k*32      + q*8, wm);
      ld8(Wm + (32+k)*32 + q*8, wq);
      ld8(Wu + k*32      + q*8, wu);
      #pragma unroll
      for(int j=0;j<8;j++){ apv[j]+=hk*wm[j]; aqv[j]+=hk*wq[j]; arv[j]+=hk*wu[j]; }
    }
  }
  st8(P + (size_t)n*32 + q*8, apv);
  st8(R + (size_t)n*32 + q*8, arv);
  half8 qo;
  #pragma unroll
  for(int k=0;k<8;k++) qo[k] = (_Float16)aqv[k];
  *(half8*)(Qh + (size_t)n*32 + q*8) = qo;
}

#define CHUNK 52
__global__ __launch_bounds__(1024) void scan_kernel(const int* __restrict__ deg, int* __restrict__ row_ptr){
  __shared__ int sums[1024];
  int t = threadIdx.x;
  int base = t*CHUNK;
  int4 v[13];
  int ssum = 0;
  #pragma unroll
  for(int i=0;i<13;i++){
    int idx = base + 4*i;
    if(idx + 3 < NN){
      v[i] = ((const int4*)deg)[(base>>2)+i];
    } else {
      v[i].x = (idx+0<NN)?deg[idx+0]:0; v[i].y = (idx+1<NN)?deg[idx+1]:0;
      v[i].z = (idx+2<NN)?deg[idx+2]:0; v[i].w = (idx+3<NN)?deg[idx+3]:0;
    }
    ssum += v[i].x + v[i].y + v[i].z + v[i].w;
  }
  sums[t]=ssum;
  __syncthreads();
  for(int off=1; off<1024; off<<=1){
    int vv = (t>=off) ? sums[t-off] : 0;
    __syncthreads();
    sums[t] += vv;
    __syncthreads();
  }
  int run = (t>0) ? sums[t-1] : 0;
  #pragma unroll
  for(int i=0;i<13;i++){
    int idx = base + 4*i;
    int4 o;
    o.x = run; run += v[i].x;
    o.y = run; run += v[i].y;
    o.z = run; run += v[i].z;
    o.w = run; run += v[i].w;
    if(idx + 3 < NN){
      ((int4*)row_ptr)[(base>>2)+i] = o;
    } else {
      if(idx+0<NN) row_ptr[idx+0]=o.x;
      if(idx+1<NN) row_ptr[idx+1]=o.y;
      if(idx+2<NN) row_ptr[idx+2]=o.z;
      if(idx+3<NN) row_ptr[idx+3]=o.w;
    }
  }
  if(t==1023) row_ptr[NN] = sums[1023];
}

__global__ __launch_bounds__(256) void fill_kernel(const int* __restrict__ ei,
    const int* __restrict__ row_ptr, const int* __restrict__ rank, int* __restrict__ csr_src){
  int t = blockIdx.x*256 + threadIdx.x;
  if(t < NE/4){
    int4 d  = ((const int4*)(ei + NE))[t];
    int4 sv = ((const int4*)ei)[t];
    int4 rk = ((const int4*)rank)[t];
    csr_src[row_ptr[d.x] + rk.x] = sv.x;
    csr_src[row_ptr[d.y] + rk.y] = sv.y;
    csr_src[row_ptr[d.z] + rk.z] = sv.z;
    csr_src[row_ptr[d.w] + rk.w] = sv.w;
  }
}

// -------- message+aggregate: 4 lanes per edge (slot,q), one 64B line per edge --------
__global__ __launch_bounds__(256) void msg_kernel(
    const float* __restrict__ P, const _Float16* __restrict__ Qh,
    const int* __restrict__ row_ptr, const int* __restrict__ csr_src,
    const float* __restrict__ mg, const float* __restrict__ mb,
    float* __restrict__ aggO)
{
  int tid = blockIdx.x*256 + threadIdx.x;   // grid = NN*16 exactly
  int n = tid >> 4;
  int s = tid & 15;
  int slot = s >> 2;
  int q = s & 3;
  float mgq[8], mbq[8], p8[8];
  ld8(mg + q*8, mgq); ld8(mb + q*8, mbq);
  ld8(P + (size_t)n*32 + q*8, p8);
  float agg8[8] = {0,0,0,0,0,0,0,0};
  int e0 = row_ptr[n], e1 = row_ptr[n+1];
  int e = e0 + slot;
  int src = (e < e1) ? csr_src[e] : 0;
  half8 qv = *(const half8*)(Qh + (size_t)src*32 + q*8);
  while(e < e1){
    int e2 = e + 4;
    int src2 = (e2 < e1) ? csr_src[e2] : 0;
    half8 qv2 = *(const half8*)(Qh + (size_t)src2*32 + q*8);
    float v[8];
    #pragma unroll
    for(int k=0;k<8;k++) v[k] = p8[k] + (float)qv[k];
    float ps = ((v[0]+v[1])+(v[2]+v[3])) + ((v[4]+v[5])+(v[6]+v[7]));
    ps += __shfl_xor(ps,1); ps += __shfl_xor(ps,2);
    float mean = ps * 0.03125f;
    float vs = 0.f;
    #pragma unroll
    for(int k=0;k<8;k++){ float dd = v[k]-mean; vs += dd*dd; v[k]=dd; }
    vs += __shfl_xor(vs,1); vs += __shfl_xor(vs,2);
    float rstd = rsqrtf(vs*0.03125f + LN_EPS);
    #pragma unroll
    for(int k=0;k<8;k++) agg8[k] += gelu_f(v[k]*rstd*mgq[k] + mbq[k]);
    qv = qv2; e = e2;
  }
  #pragma unroll
  for(int k=0;k<8;k++) agg8[k] += __shfl_xor(agg8[k], 4);
  #pragma unroll
  for(int k=0;k<8;k++) agg8[k] += __shfl_xor(agg8[k], 8);
  if(slot==0) st8(aggO + (size_t)n*32 + q*8, agg8);
}

// -------- update MLP + next-layer PQR, 4 lanes/node --------
__global__ __launch_bounds__(256) void upd_pqr_kernel(
    const float* __restrict__ aggI, const float* __restrict__ Rio,
    const float* __restrict__ Ub,
    const float* __restrict__ ug, const float* __restrict__ ub,
    const float* __restrict__ Wm2, const float* __restrict__ bm2,
    const float* __restrict__ Wu2, const float* __restrict__ bu2,
    float* __restrict__ h,
    float* __restrict__ P, _Float16* __restrict__ Qh, float* __restrict__ Rout)
{
  int t = blockIdx.x*256 + threadIdx.x;
  int n = t >> 2, q = t & 3;
  if(n >= NN) return;
  int base = threadIdx.x & 60;
  float aggq[8], uq[8];
  ld8(aggI + (size_t)n*32 + q*8, aggq);
  ld8(Rio  + (size_t)n*32 + q*8, uq);
  #pragma unroll
  for(int m=0;m<4;m++){
    #pragma unroll
    for(int kk=0;kk<8;kk++){
      float a = __shfl(aggq[kk], base|m);
      float w[8]; ld8(Ub + (m*8+kk)*32 + q*8, w);
      #pragma unroll
      for(int j=0;j<8;j++) uq[j] += a * w[j];
    }
  }
  float sm = ((uq[0]+uq[1])+(uq[2]+uq[3])) + ((uq[4]+uq[5])+(uq[6]+uq[7]));
  sm += __shfl_xor(sm,1); sm += __shfl_xor(sm,2);
  float mean = sm * 0.03125f;
  float vs = 0.f;
  #pragma unroll
  for(int j=0;j<8;j++){ float d = uq[j]-mean; vs += d*d; uq[j]=d; }
  vs += __shfl_xor(vs,1); vs += __shfl_xor(vs,2);
  float rstd = rsqrtf(vs*0.03125f + LN_EPS);
  float ugq[8], ubq[8], hq[8];
  ld8(ug+q*8, ugq); ld8(ub+q*8, ubq);
  ld8(h + (size_t)n*32 + q*8, hq);
  #pragma unroll
  for(int j=0;j<8;j++) hq[j] += gelu_f(uq[j]*rstd*ugq[j] + ubq[j]);
  st8(h + (size_t)n*32 + q*8, hq);
  // next-layer PQR
  float apv[8], aqv[8], arv[8];
  ld8(bm2+q*8, apv); ld8(bu2+q*8, arv);
  #pragma unroll
  for(int j=0;j<8;j++) aqv[j]=0.f;
  #pragma unroll
  for(int m=0;m<4;m++){
    #pragma unroll
    for(int kk=0;kk<8;kk++){
      float hk = __shfl(hq[kk], base|m);
      int k = m*8+kk;
      float wm[8],wq[8],wu[8];
      ld8(Wm2 + k*32      + q*8, wm);
      ld8(Wm2 + (32+k)*32 + q*8, wq);
      ld8(Wu2 + k*32      + q*8, wu);
      #pragma unroll
      for(int j=0;j<8;j++){ apv[j]+=hk*wm[j]; aqv[j]+=hk*wq[j]; arv[j]+=hk*wu[j]; }
    }
  }
  st8(P    + (size_t)n*32 + q*8, apv);
  st8(Rout + (size_t)n*32 + q*8, arv);
  half8 qo;
  #pragma unroll
  for(int k=0;k<8;k++) qo[k] = (_Float16)aqv[k];
  *(half8*)(Qh + (size_t)n*32 + q*8) = qo;
}

// -------- last update + final node matmul, 4 lanes/node, split-half fp16 y --------
__global__ __launch_bounds__(256) void upd_fin_kernel(
    const float* __restrict__ aggI, const float* __restrict__ Rio,
    const float* __restrict__ Ub,
    const float* __restrict__ ug, const float* __restrict__ ub,
    const float* __restrict__ h, const float* __restrict__ pre,
    const float* __restrict__ fW1, const float* __restrict__ fbng,
    _Float16* __restrict__ y1, _Float16* __restrict__ y2)
{
  int t = blockIdx.x*256 + threadIdx.x;
  int n = t >> 2, q = t & 3;
  if(n >= NN) return;
  int base = threadIdx.x & 60;
  const float rs = rsqrtf(1.0f + LN_EPS);
  float aggq[8], uq[8];
  ld8(aggI + (size_t)n*32 + q*8, aggq);
  ld8(Rio  + (size_t)n*32 + q*8, uq);
  #pragma unroll
  for(int m=0;m<4;m++){
    #pragma unroll
    for(int kk=0;kk<8;kk++){
      float a = __shfl(aggq[kk], base|m);
      float w[8]; ld8(Ub + (m*8+kk)*32 + q*8, w);
      #pragma unroll
      for(int j=0;j<8;j++) uq[j] += a * w[j];
    }
  }
  float sm = ((uq[0]+uq[1])+(uq[2]+uq[3])) + ((uq[4]+uq[5])+(uq[6]+uq[7]));
  sm += __shfl_xor(sm,1); sm += __shfl_xor(sm,2);
  float mean = sm * 0.03125f;
  float vs = 0.f;
  #pragma unroll
  for(int j=0;j<8;j++){ float d = uq[j]-mean; vs += d*d; uq[j]=d; }
  vs += __shfl_xor(vs,1); vs += __shfl_xor(vs,2);
  float rstd = rsqrtf(vs*0.03125f + LN_EPS);
  float ugq[8], ubq[8], hq[8], pq[8];
  ld8(ug+q*8, ugq); ld8(ub+q*8, ubq);
  ld8(h   + (size_t)n*32 + q*8, hq);
  ld8(pre + (size_t)n*32 + q*8, pq);
  #pragma unroll
  for(int j=0;j<8;j++) hq[j] += gelu_f(uq[j]*rstd*ugq[j] + ubq[j]) + pq[j];
  // y slice [16q,16q+16) of 64
  float acc[16];
  #pragma unroll
  for(int j=0;j<16;j++) acc[j]=0.f;
  #pragma unroll
  for(int m=0;m<4;m++){
    #pragma unroll
    for(int kk=0;kk<8;kk++){
      float hk = __shfl(hq[kk], base|m);
      float w[16]; ld16(fW1 + (m*8+kk)*64 + q*16, w);
      #pragma unroll
      for(int j=0;j<16;j++) acc[j] += hk * w[j];
    }
  }
  float fg[16]; ld16(fbng + q*16, fg);
  half8 o0, o1;
  #pragma unroll
  for(int k=0;k<8;k++){
    o0[k] = (_Float16)(acc[k]   * (fg[k]*rs));
    o1[k] = (_Float16)(acc[8+k] * (fg[8+k]*rs));
  }
  _Float16* dst = (q<2) ? (y1 + (size_t)n*32 + q*16) : (y2 + (size_t)n*32 + (q-2)*16);
  ((half8*)dst)[0] = o0; ((half8*)dst)[1] = o1;
}

// ---------------- final per-edge: 4 lanes per edge, feature-split passes ----------------
__global__ __launch_bounds__(256) void finalA_kernel(
    const _Float16* __restrict__ y, const int* __restrict__ ei,
    const float* __restrict__ cvec, const float* __restrict__ W2,
    const float* __restrict__ b2, float* __restrict__ out)
{
  int t = blockIdx.x*256 + threadIdx.x;   // grid = NE*4 exactly
  int e = t >> 2, q = t & 3;
  int s = __builtin_nontemporal_load(ei + e);
  int d = __builtin_nontemporal_load(ei + NE + e);
  half8 a8 = *(const half8*)(y + (size_t)d*32 + q*8);
  half8 c8 = *(const half8*)(y + (size_t)s*32 + q*8);
  float cq[8]; ld8(cvec + q*8, cq);
  float w[24]; ld8(W2+q*24, w); ld8(W2+q*24+8, w+8); ld8(W2+q*24+16, w+16);
  float o0=0.f,o1=0.f,o2=0.f;
  #pragma unroll
  for(int k=0;k<8;k++){
    float tt = gelu_f(((float)a8[k]-(float)c8[k]) + cq[k]);
    o0 += tt*w[3*k]; o1 += tt*w[3*k+1]; o2 += tt*w[3*k+2];
  }
  o0 += __shfl_xor(o0,1); o0 += __shfl_xor(o0,2);
  o1 += __shfl_xor(o1,1); o1 += __shfl_xor(o1,2);
  o2 += __shfl_xor(o2,1); o2 += __shfl_xor(o2,2);
  float ov = (q==0) ? o0 + b2[0] : (q==1) ? o1 + b2[1] : o2 + b2[2];
  if(q < 3) __builtin_nontemporal_store(ov, out + (size_t)e*3 + q);
}

__global__ __launch_bounds__(256) void finalB_kernel(
    const _Float16* __restrict__ y, const int* __restrict__ ei,
    const float* __restrict__ cvec, const float* __restrict__ W2,
    float* __restrict__ out)
{
  int t = blockIdx.x*256 + threadIdx.x;
  int e = t >> 2, q = t & 3;
  float prev = 0.f;
  if(q < 3) prev = __builtin_nontemporal_load(out + (size_t)e*3 + q);
  int s = __builtin_nontemporal_load(ei + e);
  int d = __builtin_nontemporal_load(ei + NE + e);
  half8 a8 = *(const half8*)(y + (size_t)d*32 + q*8);
  half8 c8 = *(const half8*)(y + (size_t)s*32 + q*8);
  float cq[8]; ld8(cvec + q*8, cq);
  float w[24]; ld8(W2+q*24, w); ld8(W2+q*24+8, w+8); ld8(W2+q*24+16, w+16);
  float o0=0.f,o1=0.f,o2=0.f;
  #pragma unroll
  for(int k=0;k<8;k++){
    float tt = gelu_f(((float)a8[k]-(float)c8[k]) + cq[k]);
    o0 += tt*w[3*k]; o1 += tt*w[3*k+1]; o2 += tt*w[3*k+2];
  }
  o0 += __shfl_xor(o0,1); o0 += __shfl_xor(o0,2);
  o1 += __shfl_xor(o1,1); o1 += __shfl_xor(o1,2);
  o2 += __shfl_xor(o2,1); o2 += __shfl_xor(o2,2);
  float ov = prev + ((q==0) ? o0 : (q==1) ? o1 : o2);
  if(q < 3) __builtin_nontemporal_store(ov, out + (size_t)e*3 + q);
}

extern "C" void kernel_launch(void* const* d_in, const int* in_sizes, int n_in,
                              void* d_out, int out_size, void* d_ws, size_t ws_size,
                              hipStream_t stream)
{
  (void)in_sizes; (void)n_in; (void)out_size; (void)ws_size;
  const float* x     = (const float*)d_in[0];
  const int*   ei    = (const int*)d_in[1];
  const float* eW1   = (const float*)d_in[2];
  const float* eb1   = (const float*)d_in[3];
  const float* ebn1g = (const float*)d_in[4];
  const float* ebn1b = (const float*)d_in[5];
  const float* eW2   = (const float*)d_in[6];
  const float* eb2   = (const float*)d_in[7];
  const float* ebn2g = (const float*)d_in[8];
  const float* ebn2b = (const float*)d_in[9];
  const float* msgW  = (const float*)d_in[10];
  const float* msgb  = (const float*)d_in[11];
  const float* msglng= (const float*)d_in[12];
  const float* msglnb= (const float*)d_in[13];
  const float* updW  = (const float*)d_in[14];
  const float* updb  = (const float*)d_in[15];
  const float* updlng= (const float*)d_in[16];
  const float* updlnb= (const float*)d_in[17];
  const float* fW1   = (const float*)d_in[18];
  const float* fb1   = (const float*)d_in[19];
  const float* fbng  = (const float*)d_in[20];
  const float* fbnb  = (const float*)d_in[21];
  const float* fW2   = (const float*)d_in[22];
  const float* fb2   = (const float*)d_in[23];
  float* out = (float*)d_out;

  float* f   = (float*)d_ws;
  float* h   = f;
  float* pre = f + 1*(size_t)NN*32;
  float* P   = f + 2*(size_t)NN*32;
  float* R   = f + 3*(size_t)NN*32;
  float* agg = f + 4*(size_t)NN*32;
  _Float16* Qh = (_Float16*)(f + 5*(size_t)NN*32);   // NN*32 halves = NN*16 floats
  _Float16* y1 = (_Float16*)P;                        // NN*32 halves
  _Float16* y2 = y1 + (size_t)NN*32;                  // NN*32 halves
  float* cvec  = f + 5*(size_t)NN*32 + (size_t)NN*16; // 64 floats
  int* ip      = (int*)(cvec + 64);
  int* cnt     = ip;              // NN
  int* row_ptr = ip + NN;         // NN+1 (padded to NN+4)
  int* csr     = ip + 2*NN + 4;   // NE
  int* rank    = (int*)agg;       // NE ints, aliases agg (free until msg)

  hipMemsetAsync(cnt, 0, NN*sizeof(int), stream);
  hist_embed_kernel<<<HIST_B + EMB_B, 256, 0, stream>>>(ei, cnt, rank,
      x, eW1, eb1, ebn1g, ebn1b, eW2, eb2, ebn2g, ebn2b,
      msgW, msgb, updW, updb,
      fb1, fbng, fbnb,
      h, pre, P, Qh, R, cvec);
  scan_kernel<<<1, 1024, 0, stream>>>(cnt, row_ptr);
  fill_kernel<<<HIST_B, 256, 0, stream>>>(ei, row_ptr, rank, csr);

  for(int l=0; l<3; l++){
    msg_kernel<<<(NN*16)/256, 256, 0, stream>>>(P, Qh, row_ptr, csr,
        msglng + l*32, msglnb + l*32, agg);
    if(l < 2){
      upd_pqr_kernel<<<EMB_B, 256, 0, stream>>>(agg, R,
          updW + l*2048 + 1024, updlng + l*32, updlnb + l*32,
          msgW + (l+1)*2048, msgb + (l+1)*32,
          updW + (l+1)*2048, updb + (l+1)*32,
          h, P, Qh, R);
    } else {
      upd_fin_kernel<<<EMB_B, 256, 0, stream>>>(agg, R,
          updW + l*2048 + 1024, updlng + l*32, updlnb + l*32,
          h, pre, fW1, fbng, y1, y2);
    }
  }

  finalA_kernel<<<(NE*4)/256, 256, 0, stream>>>(y1, ei, cvec,      fW2,      fb2, out);
  finalB_kernel<<<(NE*4)/256, 256, 0, stream>>>(y2, ei, cvec + 32, fW2 + 96, out);
}